// Round 11
// baseline (3015.220 us; speedup 1.0000x reference)
//
#include <hip/hip_runtime.h>

typedef unsigned int u32;
typedef unsigned long long u64;
typedef float v2f __attribute__((ext_vector_type(2)));

#define NB 16
#define NPT 1024
#define NP 512
#define NS 32
#define DF 64
#define RAD2 0.04f
#define EPSQ 1e-5f
#define CNTF 786432.0f   // 48*512*32
#define NGRP 8192        // NB*NP
#define TCAP 96
#define TSLOT 128
#define NTILE_MAX 2731
#define NBLK 256         // persistent grid: 1 block per CU (>=2 fit -> all resident)
#define NTHR 384
#define NBW (NBLK*6 - 8) // ball waves

// --- np-matching (contraction-proof) arithmetic -------------------------
__device__ __forceinline__ float rmul(float a, float b){ return __fmul_rn(a,b); }
__device__ __forceinline__ float radd(float a, float b){ return __fadd_rn(a,b); }
__device__ __forceinline__ float sq3(float a, float b, float c){
  return radd(radd(rmul(a,a), rmul(b,b)), rmul(c,c));
}

__device__ __forceinline__ float wave_sum64(float v){
  #pragma unroll
  for(int m=1;m<64;m<<=1) v += __shfl_xor(v, m, 64);
  return v;
}
__device__ __forceinline__ float half_sum32(float v){
  #pragma unroll
  for(int m=1;m<32;m<<=1) v += __shfl_xor(v, m, 64);
  return v;
}

// DPP max-combine on u64 key (strict >).
#define DPPK(CTRL) do{ \
  unsigned _lo = (unsigned)k, _hi = (unsigned)(k>>32); \
  unsigned _mlo = (unsigned)__builtin_amdgcn_mov_dpp((int)_lo, (CTRL), 0xF, 0xF, true); \
  unsigned _mhi = (unsigned)__builtin_amdgcn_mov_dpp((int)_hi, (CTRL), 0xF, 0xF, true); \
  u64 _mk = ((u64)_mhi<<32) | _mlo; \
  k = (_mk > k) ? _mk : k; \
}while(0)

// ---- grid barrier: monotonic counter, agent scope, memset to 0 per launch.
// __syncthreads drains each wave's stores (compiler emits vmcnt(0) before
// s_barrier); thread0's acq_rel add publishes, acquire spin invalidates.
__device__ __forceinline__ void gbar(int* bar, int phase){
  __syncthreads();
  if(threadIdx.x == 0){
    __hip_atomic_fetch_add(bar, 1, __ATOMIC_ACQ_REL, __HIP_MEMORY_SCOPE_AGENT);
    const int tgt = phase * NBLK;
    const u64 t0 = __builtin_amdgcn_s_memrealtime();
    while(__hip_atomic_load(bar, __ATOMIC_ACQUIRE, __HIP_MEMORY_SCOPE_AGENT) < tgt){
      __builtin_amdgcn_s_sleep(16);
      if(__builtin_amdgcn_s_memrealtime() - t0 > 2000000ull) break;  // 20ms backstop
    }
  }
  __syncthreads();
}

// ======================= FPS body (r10 verbatim; 2 batches per wave) ========
__device__ void fps_body(int bid, int lane, const float* __restrict__ xyz,
                         float* __restrict__ out0, int* __restrict__ farIdx,
                         float4* plds){
#pragma clang fp contract(off)
  __builtin_amdgcn_s_setprio(3);
  const int half = lane >> 5;
  const int hl   = lane & 31;
  const int b    = 2*bid + half;
  const float* xb = xyz + b*3*NPT;

  v2f px2[16], py2[16], pz2[16], dist2[16];
  u32 loj[32];
  #pragma unroll
  for(int i=0;i<16;i++){
    const int n0 = 64*i + hl, n1 = n0 + 32;
    float x0v = xb[n0],        x1v = xb[n1];
    float y0v = xb[NPT+n0],    y1v = xb[NPT+n1];
    float z0v = xb[2*NPT+n0],  z1v = xb[2*NPT+n1];
    px2[i].x = x0v; px2[i].y = x1v;
    py2[i].x = y0v; py2[i].y = y1v;
    pz2[i].x = z0v; pz2[i].y = z1v;
    loj[2*i]   = 1023u - (u32)n0;
    loj[2*i+1] = 1023u - (u32)n1;
    plds[(half<<10) + n0] = make_float4(x0v, y0v, z0v, 0.f);
    plds[(half<<10) + n1] = make_float4(x1v, y1v, z1v, 0.f);
  }
  float sx=0.f, sy=0.f, sz=0.f;
  #pragma unroll
  for(int i=0;i<16;i++){
    sx += px2[i].x; sx += px2[i].y;
    sy += py2[i].x; sy += py2[i].y;
    sz += pz2[i].x; sz += pz2[i].y;
  }
  sx = half_sum32(sx); sy = half_sum32(sy); sz = half_sum32(sz);
  const float cx = sx/1024.f, cy = sy/1024.f, cz = sz/1024.f;
  {
    v2f cx2; cx2.x=cx; cx2.y=cx;
    v2f cy2; cy2.x=cy; cy2.y=cy;
    v2f cz2; cz2.x=cz; cz2.y=cz;
    #pragma unroll
    for(int i=0;i<16;i++){
      v2f dx = px2[i]-cx2, dy = py2[i]-cy2, dz = pz2[i]-cz2;
      v2f m1 = dx*dx, m2 = dy*dy, a1 = m1+m2, m3 = dz*dz, s2 = a1+m3;
      dist2[i].x = fminf(1e10f, s2.x);
      dist2[i].y = fminf(1e10f, s2.y);
    }
  }
  auto reduce2 = [&](int& fA, int& fB){
    u64 kk[16];
    #pragma unroll
    for(int i=0;i<16;i++){
      float a = dist2[i].x, bb = dist2[i].y;
      bool tk = bb > a;                       // tie -> left (lower n)
      float dw = tk ? bb : a;
      u32   lw = tk ? loj[2*i+1] : loj[2*i];
      kk[i] = ((u64)__float_as_uint(dw)<<32) | lw;
    }
    #pragma unroll
    for(int i=0;i<8;i++){ u64 l=kk[2*i], r=kk[2*i+1]; kk[i] = (r>l)?r:l; }
    #pragma unroll
    for(int i=0;i<4;i++){ u64 l=kk[2*i], r=kk[2*i+1]; kk[i] = (r>l)?r:l; }
    #pragma unroll
    for(int i=0;i<2;i++){ u64 l=kk[2*i], r=kk[2*i+1]; kk[i] = (r>l)?r:l; }
    u64 k = (kk[1]>kk[0]) ? kk[1] : kk[0];
    DPPK(0xB1); DPPK(0x4E); DPPK(0x124); DPPK(0x128); DPPK(0x142);
    unsigned lo = (unsigned)k;
    fA = 1023 - __builtin_amdgcn_readlane((int)lo, 31);
    fB = 1023 - __builtin_amdgcn_readlane((int)lo, 63);
  };

  __asm__ volatile("s_waitcnt lgkmcnt(0)" ::: "memory");
  int farA, farB;
  reduce2(farA, farB);
  for(int it=0; it<NP; ++it){
    const int farv = (lane & 32) ? farB : farA;
    const float4 qv = plds[(half<<10) + farv];
    if(hl == 0){
      out0[(b*3+0)*NP + it] = qv.x;
      out0[(b*3+1)*NP + it] = qv.y;
      out0[(b*3+2)*NP + it] = qv.z;
      farIdx[b*NP + it] = farv;
    }
    v2f qx2; qx2.x=qv.x; qx2.y=qv.x;
    v2f qy2; qy2.x=qv.y; qy2.y=qv.y;
    v2f qz2; qz2.x=qv.z; qz2.y=qv.z;
    #pragma unroll
    for(int i=0;i<16;i++){
      v2f dx = px2[i]-qx2, dy = py2[i]-qy2, dz = pz2[i]-qz2;
      v2f m1 = dx*dx, m2 = dy*dy, a1 = m1+m2, m3 = dz*dz, s2 = a1+m3;
      dist2[i].x = fminf(dist2[i].x, s2.x);
      dist2[i].y = fminf(dist2[i].y, s2.y);
    }
    reduce2(farA, farB);
  }
  __builtin_amdgcn_s_setprio(0);
}

// ======================= ball row (r10 verbatim) =======================
__device__ void ball_row(int row, int lane, const float* __restrict__ xyz,
                         int* __restrict__ idxb_full, int* __restrict__ cnt_full){
  const int b = row >> 10;
  const int nc = row & 1023;
  const float* xb = xyz + b*3*NPT;
  const float s0 = xb[nc], s1 = xb[NPT+nc], s2 = xb[2*NPT+nc];
  const float ss = sq3(s0,s1,s2);
  int base = 0;
  int* rowp = idxb_full + row*NS;
  for(int chk=0; chk<16 && base<NS; ++chk){
    const int n = chk*64 + lane;
    float d0 = xb[n], d1 = xb[NPT+n], d2 = xb[2*NPT+n];
    float dd = sq3(d0,d1,d2);
    float p  = radd(radd(rmul(s0,d0), rmul(s1,d1)), rmul(s2,d2));
    float sqr = radd(radd(rmul(-2.0f,p), ss), dd);
    bool inc = !(sqr > RAD2);
    u64 mask = __ballot(inc);
    if(inc){
      int slot = base + __popcll(mask & ((1ull<<lane)-1ull));
      if(slot < NS) rowp[slot] = n;
    }
    base += __popcll(mask);
  }
  if(lane==0) cnt_full[row] = (base < NS) ? base : NS;
}

// ======================= pts transpose unit =======================
__device__ void tp_unit(int w, int lane, const float* __restrict__ pts,
                        float* __restrict__ ptsT){
  const int b3 = w >> 4, n0 = (w & 15) << 6;
  const float* src = pts + (((size_t)b3*64 + lane) << 10);
  float* dst = ptsT + (((size_t)b3*1024 + n0) << 6) + lane;
  #pragma unroll 4
  for(int i=0;i<64;i++) dst[(size_t)i << 6] = src[n0 + i];
}

// ======================= pack (block 0, 384 threads) =======================
__device__ void pack384(const int* __restrict__ farIdx, const int* __restrict__ cnt_full,
                        const int* __restrict__ idxb_full, u32* __restrict__ witem,
                        int* __restrict__ ntile_dev, int* __restrict__ cntb,
                        int t, int lane, int wv, int* wsum){
  const int g0 = t*22;
  const int g1 = (g0+22 < NGRP) ? (g0+22) : NGRP;
  int s0 = 0;
  for(int g=g0; g<g1; ++g){
    const int far = farIdx[g];
    const int rid = ((g>>9)<<10) + far;
    const int cc = cnt_full[rid];
    cntb[g] = cc;
    s0 += cc;
  }
  int pre = s0;
  #pragma unroll
  for(int d=1; d<64; d<<=1){
    int v = __shfl_up(pre, d, 64);
    if(lane >= d) pre += v;
  }
  if(lane==63) wsum[wv] = pre;
  __syncthreads();
  int wo = 0;
  for(int w=0;w<wv;w++) wo += wsum[w];
  if(t == NTHR-1) *ntile_dev = (wo + pre + TCAP - 1) / TCAP;
  int m = wo + pre - s0;
  for(int g=g0; g<g1; ++g){
    const int far = farIdx[g];
    const int rid = ((g>>9)<<10) + far;
    const int cc = cntb[g];
    const int tile = m / TCAP; const int slot = m - TCAP*tile;
    const int* rp = idxb_full + rid*NS;
    for(int j=0;j<cc;j++){
      witem[tile*TSLOT + slot + j] = (u32)((g<<15) | (j<<10) | rp[j]);
    }
    m += cc;
  }
}

// ======================= pass body (r10 verbatim + trailing sync) ==========
template<int DEPTH, int PT>
__device__ void pass_body(int bi, int t, char* smraw,
  const float* __restrict__ xyz, const float* __restrict__ ptsrc,
  const float* __restrict__ W0, const float* __restrict__ W1, const float* __restrict__ W2,
  const float* __restrict__ out0, const u32* __restrict__ witem,
  const int* __restrict__ cntb,
  const float* inv1, const float* inv2,
  float* __restrict__ part, float* __restrict__ out1,
  int cache_tiles, float* __restrict__ cacheA, float* __restrict__ cacheB)
{
  float (*sq)[128][17] = (float(*)[128][17])smraw;          // [3][128][17]
  float (*wstat)[128]  = (float(*)[128])(smraw + 3*128*17*4); // [6][128]
  const int c3 = t >> 7;
  const int r  = t & 127;
  const int lane = t & 63;
  const int wv = t >> 6;

  const bool use_cache = (bi < cache_tiles);
  float* cslotA = cacheA + ((size_t)bi*TSLOT + r)*192 + (size_t)c3*64;
  float* cslotB = cacheB + ((size_t)bi*TSLOT + r)*192 + (size_t)c3*64;

  for(int i=t; i<6*128; i+=NTHR) (&wstat[0][0])[i] = 0.f;
  __syncthreads();

  const u32 w = witem[bi*TSLOT + r];
  const bool valid = (w != 0xFFFFFFFFu);
  const int bs = valid ? (int)(w >> 15) : 0;
  const int j  = valid ? (int)((w >> 10) & 31) : 1;
  const int n  = valid ? (int)(w & 1023) : 0;
  const int b = bs >> 9;
  const int s = bs & 511;
  const int b3 = b*3 + c3;
  const int cv = cntb[bs];
  const float wgt = valid ? ((j==0) ? (float)(33 - cv) : 1.0f) : 0.0f;

  // ---- layer 0 ----
  float acc64[64];
  if(DEPTH >= 2 && use_cache){
    #pragma unroll
    for(int q=0;q<16;q++){
      float4 v = ((const float4*)cslotA)[q];
      acc64[4*q]=v.x; acc64[4*q+1]=v.y; acc64[4*q+2]=v.z; acc64[4*q+3]=v.w;
    }
  } else {
    const float gx = xyz[b3*NPT + n];
    const float cx = out0[b3*NP + s];
    float x0[66];
    x0[0] = gx - cx;
    x0[1] = gx;
    if constexpr(PT){
      const float4* pr4 = reinterpret_cast<const float4*>(ptsrc + (((size_t)b3<<10) + (size_t)n)*DF);
      #pragma unroll
      for(int q=0;q<16;q++){
        float4 v = pr4[q];
        x0[2+4*q] = v.x; x0[3+4*q] = v.y; x0[4+4*q] = v.z; x0[5+4*q] = v.w;
      }
    } else {
      const float* pr = ptsrc + ((size_t)b3*DF)*NPT + n;
      #pragma unroll
      for(int c=0;c<DF;c++) x0[2+c] = pr[(size_t)c*NPT];
    }
    #pragma unroll
    for(int ch=0; ch<4; ++ch){
      #pragma unroll
      for(int oo=0;oo<16;oo++){
        const int o = ch*16+oo;
        float a = 0.f;
        #pragma unroll
        for(int c=0;c<66;c++) a = fmaf(W0[o*66+c], x0[c], a);
        acc64[o] = a;
      }
    }
    if(DEPTH == 1 && use_cache){
      #pragma unroll
      for(int q=0;q<16;q++){
        float4 v; v.x=acc64[4*q]; v.y=acc64[4*q+1]; v.z=acc64[4*q+2]; v.w=acc64[4*q+3];
        ((float4*)cslotA)[q] = v;
      }
    }
  }

  if constexpr(DEPTH == 1){
    #pragma unroll
    for(int o=0;o<64;o++){
      float v = wave_sum64(acc64[o]*acc64[o]*wgt);
      if(lane==0) wstat[wv][o] += v;
    }
    __syncthreads();
    if(t < 64){
      float sv = 0.f;
      #pragma unroll
      for(int wq=0;wq<6;wq++) sv += wstat[wq][t];
      part[bi*64 + t] = sv;
    }
    __syncthreads();
    return;
  }

  // ---- qbn1 + qrelu -> y1 ----
  float y1[64];
  #pragma unroll
  for(int ch=0; ch<4; ++ch){
    float xp16[16];
    #pragma unroll
    for(int oo=0;oo<16;oo++){
      const int o = ch*16+oo;
      float xp = acc64[o] * inv1[o];
      xp16[oo] = xp;
      sq[c3][r][oo] = xp*xp;
    }
    __syncthreads();
    #pragma unroll
    for(int oo=0;oo<16;oo++){
      float m2 = (sq[0][r][oo] + sq[1][r][oo]) + sq[2][r][oo];
      float mod = sqrtf(m2);
      float cf = (mod >= 1.f) ? 1.f : mod;
      y1[ch*16+oo] = cf * xp16[oo];
    }
    __syncthreads();
  }

  // ---- layer 1 ----
  float acc2[64];
  if(DEPTH == 3 && use_cache){
    #pragma unroll
    for(int q=0;q<16;q++){
      float4 v = ((const float4*)cslotB)[q];
      acc2[4*q]=v.x; acc2[4*q+1]=v.y; acc2[4*q+2]=v.z; acc2[4*q+3]=v.w;
    }
  } else {
    #pragma unroll
    for(int ch=0; ch<4; ++ch){
      #pragma unroll
      for(int oo=0;oo<16;oo++){
        const int o = ch*16+oo;
        float a = 0.f;
        #pragma unroll
        for(int c=0;c<64;c++) a = fmaf(W1[o*64+c], y1[c], a);
        acc2[o] = a;
      }
    }
    if(DEPTH == 2 && use_cache){
      #pragma unroll
      for(int q=0;q<16;q++){
        float4 v; v.x=acc2[4*q]; v.y=acc2[4*q+1]; v.z=acc2[4*q+2]; v.w=acc2[4*q+3];
        ((float4*)cslotB)[q] = v;
      }
    }
  }

  if constexpr(DEPTH == 2){
    #pragma unroll
    for(int o=0;o<64;o++){
      float v = wave_sum64(acc2[o]*acc2[o]*wgt);
      if(lane==0) wstat[wv][o] += v;
    }
    __syncthreads();
    if(t < 64){
      float sv = 0.f;
      #pragma unroll
      for(int wq=0;wq<6;wq++) sv += wstat[wq][t];
      part[bi*64 + t] = sv;
    }
    __syncthreads();
    return;
  }

  // ---- qbn2 + qrelu -> y2 ----
  float y2[64];
  #pragma unroll
  for(int ch=0; ch<4; ++ch){
    float xp16[16];
    #pragma unroll
    for(int oo=0;oo<16;oo++){
      const int o = ch*16+oo;
      float xp = acc2[o] * inv2[o];
      xp16[oo] = xp;
      sq[c3][r][oo] = xp*xp;
    }
    __syncthreads();
    #pragma unroll
    for(int oo=0;oo<16;oo++){
      float m2 = (sq[0][r][oo] + sq[1][r][oo]) + sq[2][r][oo];
      float mod = sqrtf(m2);
      float cf = (mod >= 1.f) ? 1.f : mod;
      y2[ch*16+oo] = cf * xp16[oo];
    }
    __syncthreads();
  }

  // ---- layer 2 + per-group serial argmax + stats3 ----
  #pragma unroll
  for(int ch=0; ch<8; ++ch){
    float a3[16];
    #pragma unroll
    for(int oo=0;oo<16;oo++){
      const int o = ch*16+oo;
      float a = 0.f;
      #pragma unroll
      for(int c=0;c<64;c++) a = fmaf(W2[o*64+c], y2[c], a);
      a3[oo] = a;
      sq[c3][r][oo] = a;          // RAW x3
    }
    __syncthreads();
    if(c3 == 0){
      #pragma unroll
      for(int oo=0;oo<16;oo++){
        float a0 = sq[0][r][oo], a1 = sq[1][r][oo], a2 = sq[2][r][oo];
        float m2 = radd(radd(rmul(a0,a0), rmul(a1,a1)), rmul(a2,a2));
        float v = wave_sum64(m2*wgt);
        if(lane==0) wstat[wv][ch*16+oo] += v;
        if(valid && j==0){
          float bvv = m2; int bjj = 0;
          for(int jj=1; jj<cv; ++jj){
            float c0 = sq[0][r+jj][oo], c1 = sq[1][r+jj][oo], c2 = sq[2][r+jj][oo];
            float mm = radd(radd(rmul(c0,c0), rmul(c1,c1)), rmul(c2,c2));
            if(mm > bvv){ bvv = mm; bjj = jj; }
          }
          const int o = ch*16+oo;
          #pragma unroll
          for(int cc=0;cc<3;cc++){
            out1[(((size_t)(3*b+cc))*128 + o)*NP + s] = sq[cc][r+bjj][oo];
          }
        }
      }
    }
    __syncthreads();
  }
  if(t < 128){
    part[bi*128 + t] = wstat[0][t] + wstat[1][t];
  }
  __syncthreads();
}

// ======================= inv computation (bit-identical to fin_kernel) =====
__device__ __forceinline__ void compute_inv(const float* __restrict__ part, int ntile, int nch,
                                            float* invsh, float (*redb)[8], int t, int lane){
  for(int o0=0; o0<nch; o0+=8){
    float s[8];
    #pragma unroll
    for(int k2=0;k2<8;k2++) s[k2]=0.f;
    if(t < 256){
      for(int i=t; i<ntile; i+=256){
        const float* pp = part + (size_t)i*nch + o0;
        #pragma unroll
        for(int k2=0;k2<8;k2++) s[k2] += pp[k2];
      }
    }
    #pragma unroll
    for(int k2=0;k2<8;k2++) s[k2] = wave_sum64(s[k2]);
    if(t < 256 && lane==0){
      #pragma unroll
      for(int k2=0;k2<8;k2++) redb[t>>6][k2] = s[k2];
    }
    __syncthreads();
    if(t < 8){
      float tot = (redb[0][t]+redb[1][t])+(redb[2][t]+redb[3][t]);
      invsh[o0+t] = 1.0f/sqrtf(tot/CNTF + EPSQ);
    }
    __syncthreads();
  }
}

// ======================= UBER kernel: whole pipeline =======================
template<int PT>
__global__ __launch_bounds__(NTHR) void uber(
  const float* __restrict__ xyz, const float* __restrict__ pts,
  const float* __restrict__ W0, const float* __restrict__ W1, const float* __restrict__ W2,
  float* __restrict__ out0, float* __restrict__ out1,
  float* __restrict__ ptsT, u32* __restrict__ witem,
  int* __restrict__ idxb_full, int* __restrict__ cnt_full,
  int* __restrict__ farIdx, int* __restrict__ cntb,
  int* __restrict__ ntile_dev, float* __restrict__ part1,
  float* __restrict__ part2, float* __restrict__ part3,
  int cache_tiles, float* __restrict__ cacheA, float* __restrict__ cacheB,
  int* __restrict__ bar)
{
  __shared__ __align__(16) char smraw[32768];
  __shared__ float invsh1[64];
  __shared__ float invsh2[64];
  __shared__ float redb[4][8];
  __shared__ float sinv;

  const int bid = blockIdx.x;
  const int t = threadIdx.x;
  const int wv = t >> 6;
  const int lane = t & 63;

  // ---- phase 0: FPS (blocks 0-7 wave 0) || ball-all || fill || transpose --
  if(bid < 8 && wv == 0){
    fps_body(bid, lane, xyz, out0, farIdx, (float4*)smraw);
  } else {
    const int widx = bid*6 + wv;
    const int bw = widx - ((widx < 48) ? ((widx+5)/6) : 8);
    for(int row=bw; row<NB*NPT; row+=NBW) ball_row(row, lane, xyz, idxb_full, cnt_full);
    if(bid >= 8){
      const int gid = (bid-8)*NTHR + t;
      for(int i=gid; i<NTILE_MAX*TSLOT; i+=(NBLK-8)*NTHR) witem[i] = 0xFFFFFFFFu;
      if constexpr(PT){
        const int w = (bid-8)*6 + wv;
        if(w < 48*16) tp_unit(w, lane, pts, ptsT);
      }
    }
  }
  gbar(bar, 1);

  // ---- phase 1: pack (block 0) ----
  if(bid == 0) pack384(farIdx, cnt_full, idxb_full, witem, ntile_dev, cntb, t, lane, wv, (int*)smraw);
  gbar(bar, 2);

  const int ntile = __hip_atomic_load(ntile_dev, __ATOMIC_ACQUIRE, __HIP_MEMORY_SCOPE_AGENT);

  // ---- phase 2: pass1 ----
  for(int bi=bid; bi<ntile; bi+=NBLK)
    pass_body<1,PT>(bi, t, smraw, xyz, PT ? ptsT : pts, W0, W1, W2, out0, witem, cntb,
                    nullptr, nullptr, part1, nullptr, cache_tiles, cacheA, cacheB);
  gbar(bar, 3);

  // ---- inv1 (redundant per block, bit-identical) + pass2 ----
  compute_inv(part1, ntile, 64, invsh1, redb, t, lane);
  for(int bi=bid; bi<ntile; bi+=NBLK)
    pass_body<2,PT>(bi, t, smraw, xyz, PT ? ptsT : pts, W0, W1, W2, out0, witem, cntb,
                    invsh1, nullptr, part2, nullptr, cache_tiles, cacheA, cacheB);
  gbar(bar, 4);

  // ---- inv2 + pass3 ----
  compute_inv(part2, ntile, 64, invsh2, redb, t, lane);
  for(int bi=bid; bi<ntile; bi+=NBLK)
    pass_body<3,PT>(bi, t, smraw, xyz, PT ? ptsT : pts, W0, W1, W2, out0, witem, cntb,
                    invsh1, invsh2, part3, out1, cache_tiles, cacheA, cacheB);
  gbar(bar, 5);

  // ---- fin3 + scale: 2 blocks per channel o ----
  {
    const int o = bid >> 1;
    const int halfp = bid & 1;
    float sum = 0.f;
    if(t < 256){ for(int i=t; i<ntile; i+=256) sum += part3[(size_t)i*128 + o]; }
    sum = wave_sum64(sum);
    if(t < 256 && lane==0) redb[t>>6][0] = sum;
    __syncthreads();
    if(t == 0){
      float tot = (redb[0][0]+redb[1][0])+(redb[2][0]+redb[3][0]);
      sinv = 1.0f/sqrtf(tot/CNTF + EPSQ);
    }
    __syncthreads();
    const float iv = sinv;
    const size_t str = (size_t)128*NP;
    if(t < 256){
      for(int k2=0;k2<16;k2++){
        const int idx = halfp*4096 + k2*256 + t;
        const int b = idx >> 9, s = idx & 511;
        size_t i0 = ((size_t)(b*3)*128 + o)*NP + s;
        float a0 = out1[i0] * iv;
        float a1 = out1[i0+str] * iv;
        float a2 = out1[i0+2*str] * iv;
        float m2 = (a0*a0 + a1*a1) + a2*a2;
        float mod = sqrtf(m2);
        float cf = (mod >= 1.f) ? 1.f : mod;
        out1[i0] = cf*a0; out1[i0+str] = cf*a1; out1[i0+2*str] = cf*a2;
      }
    }
  }
}

// ======================= host =======================
extern "C" void kernel_launch(void* const* d_in, const int* in_sizes, int n_in,
                              void* d_out, int out_size, void* d_ws, size_t ws_size,
                              hipStream_t stream){
  const float* xyz = (const float*)d_in[0];
  const float* pts = (const float*)d_in[1];
  const float* W0  = (const float*)d_in[2];
  const float* W1  = (const float*)d_in[3];
  const float* W2  = (const float*)d_in[4];
  float* out = (float*)d_out;

  char* p = (char*)d_ws;
  auto carve = [&](size_t bytes)->char*{
    char* q = p; p += (bytes + 255) & ~(size_t)255; return q;
  };
  int*   idxb_full = (int*)  carve((size_t)NB*NPT*NS*4);
  int*   cnt_full  = (int*)  carve((size_t)NB*NPT*4);
  int*   farIdx    = (int*)  carve((size_t)NGRP*4);
  int*   cntb      = (int*)  carve((size_t)NGRP*4);
  u32*   witem     = (u32*)  carve((size_t)NTILE_MAX*TSLOT*4);
  int*   ntile_dev = (int*)  carve(256);
  int*   bar       = (int*)  carve(256);
  float* part1     = (float*)carve((size_t)NTILE_MAX*64*4);
  float* part2     = (float*)carve((size_t)NTILE_MAX*64*4);
  float* part3     = (float*)carve((size_t)NTILE_MAX*128*4);
  size_t base_need = (size_t)(p - (char*)d_ws);
  float* ptsT      = (float*)p;
  const size_t pt_bytes = (size_t)48*1024*64*4;
  const bool use_pt = (ws_size >= base_need + pt_bytes + (1u<<20));

  size_t fixed = base_need + (use_pt ? pt_bytes : 0);
  const size_t per_tile = (size_t)TSLOT*192*4*2;
  int cache_tiles = 0;
  if(ws_size > fixed + per_tile)
    cache_tiles = (int)((ws_size - fixed) / per_tile);
  if(cache_tiles > NTILE_MAX) cache_tiles = NTILE_MAX;
  float* cacheA = (float*)((char*)d_ws + fixed);
  float* cacheB = cacheA + (size_t)cache_tiles*TSLOT*192;

  float* out1 = out + NB*3*NP;

  hipMemsetAsync(bar, 0, 8, stream);
  if(use_pt)
    uber<1><<<NBLK, NTHR, 0, stream>>>(xyz, pts, W0, W1, W2, out, out1, ptsT, witem,
                                       idxb_full, cnt_full, farIdx, cntb, ntile_dev,
                                       part1, part2, part3, cache_tiles, cacheA, cacheB, bar);
  else
    uber<0><<<NBLK, NTHR, 0, stream>>>(xyz, pts, W0, W1, W2, out, out1, nullptr, witem,
                                       idxb_full, cnt_full, farIdx, cntb, ntile_dev,
                                       part1, part2, part3, cache_tiles, cacheA, cacheB, bar);
}

// Round 12
// 918.360 us; speedup vs baseline: 3.2833x; 3.2833x over previous
//
#include <hip/hip_runtime.h>

typedef unsigned int u32;
typedef unsigned long long u64;
typedef float v2f __attribute__((ext_vector_type(2)));

#define NB 16
#define NPT 1024
#define NP 512
#define NS 32
#define DF 64
#define RAD2 0.04f
#define EPSQ 1e-5f
#define CNTF 786432.0f   // 48*512*32
#define NGRP 8192        // NB*NP
#define TCAP 96
#define TSLOT 128
#define NTILE_MAX 2731
#define NBALLBLK 4096    // 4096 blocks x 4 waves = 16384 ball rows
#define NFILLBLK 1366
#define NPGRID 512       // pass grid (stride loop over tiles)

// --- np-matching (contraction-proof) arithmetic -------------------------
__device__ __forceinline__ float rmul(float a, float b){ return __fmul_rn(a,b); }
__device__ __forceinline__ float radd(float a, float b){ return __fadd_rn(a,b); }
__device__ __forceinline__ float sq3(float a, float b, float c){
  return radd(radd(rmul(a,a), rmul(b,b)), rmul(c,c));
}

__device__ __forceinline__ float wave_sum64(float v){
  #pragma unroll
  for(int m=1;m<64;m<<=1) v += __shfl_xor(v, m, 64);
  return v;
}
__device__ __forceinline__ float half_sum32(float v){
  #pragma unroll
  for(int m=1;m<32;m<<=1) v += __shfl_xor(v, m, 64);
  return v;
}

// DPP max-combine on u64 key (strict >).
#define DPPK(CTRL) do{ \
  unsigned _lo = (unsigned)k, _hi = (unsigned)(k>>32); \
  unsigned _mlo = (unsigned)__builtin_amdgcn_mov_dpp((int)_lo, (CTRL), 0xF, 0xF, true); \
  unsigned _mhi = (unsigned)__builtin_amdgcn_mov_dpp((int)_hi, (CTRL), 0xF, 0xF, true); \
  u64 _mk = ((u64)_mhi<<32) | _mlo; \
  k = (_mk > k) ? _mk : k; \
}while(0)

// ======================= MEGA kernel (r10 verbatim) =======================
template<int PT>
__global__ __launch_bounds__(256) void fps_combo(const float* __restrict__ xyz,
                                                 float* __restrict__ out0,
                                                 const float* __restrict__ pts,
                                                 float* __restrict__ ptsT,
                                                 u32* __restrict__ witem,
                                                 int* __restrict__ idxb_full,
                                                 int* __restrict__ cnt_full,
                                                 int* __restrict__ farIdx){
#pragma clang fp contract(off)
  const int bid = blockIdx.x;
  const int t = threadIdx.x;

  if(bid >= 8){
    if(bid < 8 + NBALLBLK){
      const int row = (bid - 8)*4 + (t>>6);
      const int lane = t & 63;
      const int b = row >> 10;
      const int nc = row & 1023;
      const float* xb = xyz + b*3*NPT;
      const float s0 = xb[nc], s1 = xb[NPT+nc], s2 = xb[2*NPT+nc];
      const float ss = sq3(s0,s1,s2);
      int base = 0;
      int* rowp = idxb_full + row*NS;
      for(int chk=0; chk<16 && base<NS; ++chk){
        const int n = chk*64 + lane;
        float d0 = xb[n], d1 = xb[NPT+n], d2 = xb[2*NPT+n];
        float dd = sq3(d0,d1,d2);
        float p  = radd(radd(rmul(s0,d0), rmul(s1,d1)), rmul(s2,d2));
        float sqr = radd(radd(rmul(-2.0f,p), ss), dd);
        bool inc = !(sqr > RAD2);
        u64 mask = __ballot(inc);
        if(inc){
          int slot = base + __popcll(mask & ((1ull<<lane)-1ull));
          if(slot < NS) rowp[slot] = n;
        }
        base += __popcll(mask);
      }
      if(lane==0) cnt_full[row] = (base < NS) ? base : NS;
    } else {
      const int gid = (bid - 8 - NBALLBLK)*256 + t;
      if(gid < NTILE_MAX*TSLOT) witem[gid] = 0xFFFFFFFFu;
      if constexpr(PT){
        const int w = gid >> 6, ln = gid & 63;
        if(w < 48*16){
          const int b3 = w >> 4, n0 = (w & 15) << 6;
          const float* src = pts + (((size_t)b3*64 + ln) << 10);
          float* dst = ptsT + (((size_t)b3*1024 + n0) << 6) + ln;
          #pragma unroll 4
          for(int i=0;i<64;i++) dst[(size_t)i << 6] = src[n0 + i];
        }
      }
    }
    return;
  }

  // ---- FPS: 2 batches per wave ----
  __shared__ float4 plds[2048];
  if(t >= 64) return;
  __builtin_amdgcn_s_setprio(3);
  const int lane = t;
  const int half = lane >> 5;
  const int hl   = lane & 31;
  const int b    = 2*bid + half;
  const float* xb = xyz + b*3*NPT;

  v2f px2[16], py2[16], pz2[16], dist2[16];
  u32 loj[32];
  #pragma unroll
  for(int i=0;i<16;i++){
    const int n0 = 64*i + hl, n1 = n0 + 32;
    float x0v = xb[n0],        x1v = xb[n1];
    float y0v = xb[NPT+n0],    y1v = xb[NPT+n1];
    float z0v = xb[2*NPT+n0],  z1v = xb[2*NPT+n1];
    px2[i].x = x0v; px2[i].y = x1v;
    py2[i].x = y0v; py2[i].y = y1v;
    pz2[i].x = z0v; pz2[i].y = z1v;
    loj[2*i]   = 1023u - (u32)n0;
    loj[2*i+1] = 1023u - (u32)n1;
    plds[(half<<10) + n0] = make_float4(x0v, y0v, z0v, 0.f);
    plds[(half<<10) + n1] = make_float4(x1v, y1v, z1v, 0.f);
  }
  float sx=0.f, sy=0.f, sz=0.f;
  #pragma unroll
  for(int i=0;i<16;i++){
    sx += px2[i].x; sx += px2[i].y;
    sy += py2[i].x; sy += py2[i].y;
    sz += pz2[i].x; sz += pz2[i].y;
  }
  sx = half_sum32(sx); sy = half_sum32(sy); sz = half_sum32(sz);
  const float cx = sx/1024.f, cy = sy/1024.f, cz = sz/1024.f;
  {
    v2f cx2; cx2.x=cx; cx2.y=cx;
    v2f cy2; cy2.x=cy; cy2.y=cy;
    v2f cz2; cz2.x=cz; cz2.y=cz;
    #pragma unroll
    for(int i=0;i<16;i++){
      v2f dx = px2[i]-cx2, dy = py2[i]-cy2, dz = pz2[i]-cz2;
      v2f m1 = dx*dx, m2 = dy*dy, a1 = m1+m2, m3 = dz*dz, s2 = a1+m3;
      dist2[i].x = fminf(1e10f, s2.x);
      dist2[i].y = fminf(1e10f, s2.y);
    }
  }
  auto reduce2 = [&](int& fA, int& fB){
    u64 kk[16];
    #pragma unroll
    for(int i=0;i<16;i++){
      float a = dist2[i].x, bb = dist2[i].y;
      bool tk = bb > a;                       // tie -> left (lower n)
      float dw = tk ? bb : a;
      u32   lw = tk ? loj[2*i+1] : loj[2*i];
      kk[i] = ((u64)__float_as_uint(dw)<<32) | lw;
    }
    #pragma unroll
    for(int i=0;i<8;i++){ u64 l=kk[2*i], r=kk[2*i+1]; kk[i] = (r>l)?r:l; }
    #pragma unroll
    for(int i=0;i<4;i++){ u64 l=kk[2*i], r=kk[2*i+1]; kk[i] = (r>l)?r:l; }
    #pragma unroll
    for(int i=0;i<2;i++){ u64 l=kk[2*i], r=kk[2*i+1]; kk[i] = (r>l)?r:l; }
    u64 k = (kk[1]>kk[0]) ? kk[1] : kk[0];
    DPPK(0xB1); DPPK(0x4E); DPPK(0x124); DPPK(0x128); DPPK(0x142);
    unsigned lo = (unsigned)k;
    fA = 1023 - __builtin_amdgcn_readlane((int)lo, 31);
    fB = 1023 - __builtin_amdgcn_readlane((int)lo, 63);
  };

  __asm__ volatile("s_waitcnt lgkmcnt(0)" ::: "memory");
  int farA, farB;
  reduce2(farA, farB);
  for(int it=0; it<NP; ++it){
    const int farv = (lane & 32) ? farB : farA;
    const float4 qv = plds[(half<<10) + farv];
    if(hl == 0){
      out0[(b*3+0)*NP + it] = qv.x;
      out0[(b*3+1)*NP + it] = qv.y;
      out0[(b*3+2)*NP + it] = qv.z;
      farIdx[b*NP + it] = farv;
    }
    v2f qx2; qx2.x=qv.x; qx2.y=qv.x;
    v2f qy2; qy2.x=qv.y; qy2.y=qv.y;
    v2f qz2; qz2.x=qv.z; qz2.y=qv.z;
    #pragma unroll
    for(int i=0;i<16;i++){
      v2f dx = px2[i]-qx2, dy = py2[i]-qy2, dz = pz2[i]-qz2;
      v2f m1 = dx*dx, m2 = dy*dy, a1 = m1+m2, m3 = dz*dz, s2 = a1+m3;
      dist2[i].x = fminf(dist2[i].x, s2.x);
      dist2[i].y = fminf(dist2[i].y, s2.y);
    }
    reduce2(farA, farB);
  }
}

// ======================= pack (r10 verbatim) =======================
__global__ __launch_bounds__(1024) void pack_kernel(const int* __restrict__ farIdx,
                                                    const int* __restrict__ cnt_full,
                                                    const int* __restrict__ idxb_full,
                                                    u32* __restrict__ witem,
                                                    int* __restrict__ ntile_dev,
                                                    int* __restrict__ cntb){
  const int t = threadIdx.x;
  const int lane = t & 63;
  const int wv = t >> 6;
  int c[8]; int rowid[8]; int s0 = 0;
  #pragma unroll
  for(int i=0;i<8;i++){
    const int g = t*8+i;
    const int far = farIdx[g];
    rowid[i] = ((g>>9)<<10) + far;
    c[i] = cnt_full[rowid[i]];
    cntb[g] = c[i];
    s0 += c[i];
  }
  int pre = s0;
  #pragma unroll
  for(int d=1; d<64; d<<=1){
    int v = __shfl_up(pre, d, 64);
    if(lane >= d) pre += v;
  }
  __shared__ int wsum[16];
  if(lane==63) wsum[wv] = pre;
  __syncthreads();
  int wo = 0;
  #pragma unroll
  for(int w=0;w<16;w++) if(w < wv) wo += wsum[w];
  int m = wo + pre - s0;
  if(t==1023) *ntile_dev = (wo + pre + TCAP - 1) / TCAP;
  #pragma unroll
  for(int i=0;i<8;i++){
    const int g = t*8+i; const int cc = c[i];
    const int tile = m / TCAP; const int slot = m - TCAP*tile;
    const int* rp = idxb_full + rowid[i]*NS;
    for(int j=0;j<cc;j++){
      witem[tile*TSLOT + slot + j] = (u32)((g<<15) | (j<<10) | rp[j]);
    }
    m += cc;
  }
}

// ===== inv computation, bit-identical to the old fin_kernel (r11-validated)
__device__ __forceinline__ void compute_inv(const float* __restrict__ part, int ntile, int nch,
                                            float* invsh, float (*redb)[8], int t, int lane){
  for(int o0=0; o0<nch; o0+=8){
    float s[8];
    #pragma unroll
    for(int k2=0;k2<8;k2++) s[k2]=0.f;
    if(t < 256){
      for(int i=t; i<ntile; i+=256){
        const float* pp = part + (size_t)i*nch + o0;
        #pragma unroll
        for(int k2=0;k2<8;k2++) s[k2] += pp[k2];
      }
    }
    #pragma unroll
    for(int k2=0;k2<8;k2++) s[k2] = wave_sum64(s[k2]);
    if(t < 256 && lane==0){
      #pragma unroll
      for(int k2=0;k2<8;k2++) redb[t>>6][k2] = s[k2];
    }
    __syncthreads();
    if(t < 8){
      float tot = (redb[0][t]+redb[1][t])+(redb[2][t]+redb[3][t]);
      invsh[o0+t] = 1.0f/sqrtf(tot/CNTF + EPSQ);
    }
    __syncthreads();
  }
}

// ======================= Fused MLP passes (stride loop, fused inv) =========
template<int DEPTH, int PT>
__global__ __launch_bounds__(384) void pass_kernel(
  const float* __restrict__ xyz, const float* __restrict__ ptsrc,
  const float* __restrict__ W0, const float* __restrict__ W1, const float* __restrict__ W2,
  const float* __restrict__ out0, const u32* __restrict__ witem,
  const int* __restrict__ cntb, const int* __restrict__ ntile_dev,
  const float* __restrict__ part_in1, const float* __restrict__ part_in2,
  float* __restrict__ part, float* __restrict__ out1,
  int cache_tiles, float* __restrict__ cacheA, float* __restrict__ cacheB)
{
  const int t = threadIdx.x;
  const int c3 = t >> 7;
  const int r  = t & 127;
  const int lane = t & 63;
  const int wv = t >> 6;

  const int ntile = *ntile_dev;
  if(blockIdx.x >= ntile) return;

  __shared__ float sq[3][128][17];
  __shared__ float wstat[6][128];
  __shared__ float invsh1[64];
  __shared__ float invsh2[64];
  __shared__ float redb[4][8];

  if constexpr(DEPTH >= 2) compute_inv(part_in1, ntile, 64, invsh1, redb, t, lane);
  if constexpr(DEPTH == 3) compute_inv(part_in2, ntile, 64, invsh2, redb, t, lane);

  for(int bi = blockIdx.x; bi < ntile; bi += NPGRID){
    const bool use_cache = (bi < cache_tiles);
    float* cslotA = cacheA + ((size_t)bi*TSLOT + r)*192 + (size_t)c3*64;
    float* cslotB = cacheB + ((size_t)bi*TSLOT + r)*192 + (size_t)c3*64;

    for(int i=t; i<6*128; i+=384) (&wstat[0][0])[i] = 0.f;
    __syncthreads();

    const u32 w = witem[bi*TSLOT + r];
    const bool valid = (w != 0xFFFFFFFFu);
    const int bs = valid ? (int)(w >> 15) : 0;
    const int j  = valid ? (int)((w >> 10) & 31) : 1;
    const int n  = valid ? (int)(w & 1023) : 0;
    const int b = bs >> 9;
    const int s = bs & 511;
    const int b3 = b*3 + c3;
    const int cv = cntb[bs];
    const float wgt = valid ? ((j==0) ? (float)(33 - cv) : 1.0f) : 0.0f;

    float acc2[64];   // layer-1 raw accumulators (DEPTH>=2)
    bool skip01 = (DEPTH == 3) && use_cache;

    if(!skip01){
      // ---- layer 0: recompute or cacheA ----
      float acc64[64];
      if(DEPTH >= 2 && use_cache){
        #pragma unroll
        for(int q=0;q<16;q++){
          float4 v = ((const float4*)cslotA)[q];
          acc64[4*q]=v.x; acc64[4*q+1]=v.y; acc64[4*q+2]=v.z; acc64[4*q+3]=v.w;
        }
      } else {
        const float gx = xyz[b3*NPT + n];
        const float cx = out0[b3*NP + s];
        float x0[66];
        x0[0] = gx - cx;
        x0[1] = gx;
        if constexpr(PT){
          const float4* pr4 = reinterpret_cast<const float4*>(ptsrc + (((size_t)b3<<10) + (size_t)n)*DF);
          #pragma unroll
          for(int q=0;q<16;q++){
            float4 v = pr4[q];
            x0[2+4*q] = v.x; x0[3+4*q] = v.y; x0[4+4*q] = v.z; x0[5+4*q] = v.w;
          }
        } else {
          const float* pr = ptsrc + ((size_t)b3*DF)*NPT + n;
          #pragma unroll
          for(int c=0;c<DF;c++) x0[2+c] = pr[(size_t)c*NPT];
        }
        #pragma unroll
        for(int ch=0; ch<4; ++ch){
          #pragma unroll
          for(int oo=0;oo<16;oo++){
            const int o = ch*16+oo;
            float a = 0.f;
            #pragma unroll
            for(int c=0;c<66;c++) a = fmaf(W0[o*66+c], x0[c], a);
            acc64[o] = a;
          }
        }
        if(DEPTH == 1 && use_cache){
          #pragma unroll
          for(int q=0;q<16;q++){
            float4 v; v.x=acc64[4*q]; v.y=acc64[4*q+1]; v.z=acc64[4*q+2]; v.w=acc64[4*q+3];
            ((float4*)cslotA)[q] = v;
          }
        }
      }

      if constexpr(DEPTH == 1){
        #pragma unroll
        for(int o=0;o<64;o++){
          float v = wave_sum64(acc64[o]*acc64[o]*wgt);
          if(lane==0) wstat[wv][o] += v;
        }
        __syncthreads();
        if(t < 64){
          float sv = 0.f;
          #pragma unroll
          for(int wq=0;wq<6;wq++) sv += wstat[wq][t];
          part[bi*64 + t] = sv;
        }
        __syncthreads();
        continue;
      }

      // ---- qbn1 + qrelu -> y1 ----
      float y1[64];
      #pragma unroll
      for(int ch=0; ch<4; ++ch){
        float xp16[16];
        #pragma unroll
        for(int oo=0;oo<16;oo++){
          const int o = ch*16+oo;
          float xp = acc64[o] * invsh1[o];
          xp16[oo] = xp;
          sq[c3][r][oo] = xp*xp;
        }
        __syncthreads();
        #pragma unroll
        for(int oo=0;oo<16;oo++){
          float m2 = (sq[0][r][oo] + sq[1][r][oo]) + sq[2][r][oo];
          float mod = sqrtf(m2);
          float cf = (mod >= 1.f) ? 1.f : mod;
          y1[ch*16+oo] = cf * xp16[oo];
        }
        __syncthreads();
      }

      // ---- layer 1 ----
      #pragma unroll
      for(int ch=0; ch<4; ++ch){
        #pragma unroll
        for(int oo=0;oo<16;oo++){
          const int o = ch*16+oo;
          float a = 0.f;
          #pragma unroll
          for(int c=0;c<64;c++) a = fmaf(W1[o*64+c], y1[c], a);
          acc2[o] = a;
        }
      }
      if(DEPTH == 2 && use_cache){
        #pragma unroll
        for(int q=0;q<16;q++){
          float4 v; v.x=acc2[4*q]; v.y=acc2[4*q+1]; v.z=acc2[4*q+2]; v.w=acc2[4*q+3];
          ((float4*)cslotB)[q] = v;
        }
      }
    } else {
      // DEPTH==3 + cache: acc2 straight from cacheB (layer0/qbn1/GEMM1 skipped)
      #pragma unroll
      for(int q=0;q<16;q++){
        float4 v = ((const float4*)cslotB)[q];
        acc2[4*q]=v.x; acc2[4*q+1]=v.y; acc2[4*q+2]=v.z; acc2[4*q+3]=v.w;
      }
    }

    if constexpr(DEPTH == 2){
      #pragma unroll
      for(int o=0;o<64;o++){
        float v = wave_sum64(acc2[o]*acc2[o]*wgt);
        if(lane==0) wstat[wv][o] += v;
      }
      __syncthreads();
      if(t < 64){
        float sv = 0.f;
        #pragma unroll
        for(int wq=0;wq<6;wq++) sv += wstat[wq][t];
        part[bi*64 + t] = sv;
      }
      __syncthreads();
      continue;
    }

    if constexpr(DEPTH == 3){
      // ---- qbn2 + qrelu -> y2 ----
      float y2[64];
      #pragma unroll
      for(int ch=0; ch<4; ++ch){
        float xp16[16];
        #pragma unroll
        for(int oo=0;oo<16;oo++){
          const int o = ch*16+oo;
          float xp = acc2[o] * invsh2[o];
          xp16[oo] = xp;
          sq[c3][r][oo] = xp*xp;
        }
        __syncthreads();
        #pragma unroll
        for(int oo=0;oo<16;oo++){
          float m2 = (sq[0][r][oo] + sq[1][r][oo]) + sq[2][r][oo];
          float mod = sqrtf(m2);
          float cf = (mod >= 1.f) ? 1.f : mod;
          y2[ch*16+oo] = cf * xp16[oo];
        }
        __syncthreads();
      }

      // ---- layer 2 + per-group serial argmax + stats3 ----
      #pragma unroll
      for(int ch=0; ch<8; ++ch){
        #pragma unroll
        for(int oo=0;oo<16;oo++){
          const int o = ch*16+oo;
          float a = 0.f;
          #pragma unroll
          for(int c=0;c<64;c++) a = fmaf(W2[o*64+c], y2[c], a);
          sq[c3][r][oo] = a;          // RAW x3
        }
        __syncthreads();
        if(c3 == 0){
          #pragma unroll
          for(int oo=0;oo<16;oo++){
            float a0 = sq[0][r][oo], a1 = sq[1][r][oo], a2 = sq[2][r][oo];
            float m2 = radd(radd(rmul(a0,a0), rmul(a1,a1)), rmul(a2,a2));
            float v = wave_sum64(m2*wgt);
            if(lane==0) wstat[wv][ch*16+oo] += v;
            if(valid && j==0){
              float bvv = m2; int bjj = 0;
              for(int jj=1; jj<cv; ++jj){
                float c0 = sq[0][r+jj][oo], c1 = sq[1][r+jj][oo], c2 = sq[2][r+jj][oo];
                float mm = radd(radd(rmul(c0,c0), rmul(c1,c1)), rmul(c2,c2));
                if(mm > bvv){ bvv = mm; bjj = jj; }
              }
              const int o = ch*16+oo;
              #pragma unroll
              for(int cc=0;cc<3;cc++){
                out1[(((size_t)(3*b+cc))*128 + o)*NP + s] = sq[cc][r+bjj][oo];
              }
            }
          }
        }
        __syncthreads();
      }
      if(t < 128){
        part[bi*128 + t] = wstat[0][t] + wstat[1][t];
      }
      __syncthreads();
    }
  }
}

// ======================= fin3 + final qbn+qrelu fused =======================
__global__ __launch_bounds__(256) void fin3_scale(const float* __restrict__ part3,
                                                  const int* __restrict__ ntile_dev,
                                                  float* __restrict__ out){
  const int o = blockIdx.x;
  const int t = threadIdx.x;
  const int nblk = *ntile_dev;
  float sum = 0.f;
  for(int i=t; i<nblk; i+=256) sum += part3[(size_t)i*128 + o];
  sum = wave_sum64(sum);
  __shared__ float red[4];
  __shared__ float sinv;
  if((t&63)==0) red[t>>6] = sum;
  __syncthreads();
  if(t==0){
    float tot = (red[0]+red[1])+(red[2]+red[3]);
    sinv = 1.0f / sqrtf(tot/CNTF + EPSQ);
  }
  __syncthreads();
  const float iv = sinv;
  float* base = out + NB*3*NP;
  const size_t str = (size_t)128*NP;
  for(int idx=t; idx<NB*NP; idx+=256){
    const int b = idx >> 9, s = idx & 511;
    size_t i0 = ((size_t)(b*3)*128 + o)*NP + s;
    float a0 = base[i0] * iv;
    float a1 = base[i0+str] * iv;
    float a2 = base[i0+2*str] * iv;
    float m2 = (a0*a0 + a1*a1) + a2*a2;
    float mod = sqrtf(m2);
    float cf = (mod >= 1.f) ? 1.f : mod;
    base[i0] = cf*a0; base[i0+str] = cf*a1; base[i0+2*str] = cf*a2;
  }
}

// ======================= host =======================
extern "C" void kernel_launch(void* const* d_in, const int* in_sizes, int n_in,
                              void* d_out, int out_size, void* d_ws, size_t ws_size,
                              hipStream_t stream){
  const float* xyz = (const float*)d_in[0];
  const float* pts = (const float*)d_in[1];
  const float* W0  = (const float*)d_in[2];
  const float* W1  = (const float*)d_in[3];
  const float* W2  = (const float*)d_in[4];
  float* out = (float*)d_out;

  char* p = (char*)d_ws;
  auto carve = [&](size_t bytes)->char*{
    char* q = p; p += (bytes + 255) & ~(size_t)255; return q;
  };
  int*   idxb_full = (int*)  carve((size_t)NB*NPT*NS*4);
  int*   cnt_full  = (int*)  carve((size_t)NB*NPT*4);
  int*   farIdx    = (int*)  carve((size_t)NGRP*4);
  int*   cntb      = (int*)  carve((size_t)NGRP*4);
  u32*   witem     = (u32*)  carve((size_t)NTILE_MAX*TSLOT*4);
  int*   ntile_dev = (int*)  carve(256);
  float* part1     = (float*)carve((size_t)NTILE_MAX*64*4);
  float* part2     = (float*)carve((size_t)NTILE_MAX*64*4);
  float* part3     = (float*)carve((size_t)NTILE_MAX*128*4);
  size_t base_need = (size_t)(p - (char*)d_ws);
  float* ptsT      = (float*)p;
  const size_t pt_bytes = (size_t)48*1024*64*4;
  const bool use_pt = (ws_size >= base_need + pt_bytes + (1u<<20));

  size_t fixed = base_need + (use_pt ? pt_bytes : 0);
  const size_t per_tile = (size_t)TSLOT*192*4*2;
  int cache_tiles = 0;
  if(ws_size > fixed + per_tile)
    cache_tiles = (int)((ws_size - fixed) / per_tile);
  if(cache_tiles > NTILE_MAX) cache_tiles = NTILE_MAX;
  float* cacheA = (float*)((char*)d_ws + fixed);
  float* cacheB = cacheA + (size_t)cache_tiles*TSLOT*192;

  float* out1 = out + NB*3*NP;
  const int nblk = 8 + NBALLBLK + NFILLBLK;

  if(use_pt) fps_combo<1><<<nblk, 256, 0, stream>>>(xyz, out, pts, ptsT, witem, idxb_full, cnt_full, farIdx);
  else       fps_combo<0><<<nblk, 256, 0, stream>>>(xyz, out, pts, nullptr, witem, idxb_full, cnt_full, farIdx);

  pack_kernel<<<1, 1024, 0, stream>>>(farIdx, cnt_full, idxb_full, witem, ntile_dev, cntb);

  if(use_pt){
    pass_kernel<1,1><<<NPGRID, 384, 0, stream>>>(xyz, ptsT, W0, W1, W2, out, witem, cntb, ntile_dev, nullptr, nullptr, part1, nullptr, cache_tiles, cacheA, cacheB);
    pass_kernel<2,1><<<NPGRID, 384, 0, stream>>>(xyz, ptsT, W0, W1, W2, out, witem, cntb, ntile_dev, part1, nullptr, part2, nullptr, cache_tiles, cacheA, cacheB);
    pass_kernel<3,1><<<NPGRID, 384, 0, stream>>>(xyz, ptsT, W0, W1, W2, out, witem, cntb, ntile_dev, part1, part2, part3, out1, cache_tiles, cacheA, cacheB);
  } else {
    pass_kernel<1,0><<<NPGRID, 384, 0, stream>>>(xyz, pts, W0, W1, W2, out, witem, cntb, ntile_dev, nullptr, nullptr, part1, nullptr, cache_tiles, cacheA, cacheB);
    pass_kernel<2,0><<<NPGRID, 384, 0, stream>>>(xyz, pts, W0, W1, W2, out, witem, cntb, ntile_dev, part1, nullptr, part2, nullptr, cache_tiles, cacheA, cacheB);
    pass_kernel<3,0><<<NPGRID, 384, 0, stream>>>(xyz, pts, W0, W1, W2, out, witem, cntb, ntile_dev, part1, part2, part3, out1, cache_tiles, cacheA, cacheB);
  }
  fin3_scale<<<128, 256, 0, stream>>>(part3, ntile_dev, out);
}

// Round 13
// 744.992 us; speedup vs baseline: 4.0473x; 1.2327x over previous
//
#include <hip/hip_runtime.h>

typedef unsigned int u32;
typedef unsigned long long u64;
typedef float v2f __attribute__((ext_vector_type(2)));

#define NB 16
#define NPT 1024
#define NP 512
#define NS 32
#define DF 64
#define RAD2 0.04f
#define EPSQ 1e-5f
#define CNTF 786432.0f   // 48*512*32
#define NGRP 8192        // NB*NP
#define TCAP 96
#define TSLOT 128
#define NTILE_MAX 2731
#define NBALLBLK 4096    // 4096 blocks x 4 waves = 16384 ball rows
#define NFILLBLK 1366

// --- np-matching (contraction-proof) arithmetic -------------------------
__device__ __forceinline__ float rmul(float a, float b){ return __fmul_rn(a,b); }
__device__ __forceinline__ float radd(float a, float b){ return __fadd_rn(a,b); }
__device__ __forceinline__ float sq3(float a, float b, float c){
  return radd(radd(rmul(a,a), rmul(b,b)), rmul(c,c));
}

__device__ __forceinline__ float wave_sum64(float v){
  #pragma unroll
  for(int m=1;m<64;m<<=1) v += __shfl_xor(v, m, 64);
  return v;
}
__device__ __forceinline__ float half_sum32(float v){
  #pragma unroll
  for(int m=1;m<32;m<<=1) v += __shfl_xor(v, m, 64);
  return v;
}

// DPP max-combine on u64 key (strict >).
#define DPPK(CTRL) do{ \
  unsigned _lo = (unsigned)k, _hi = (unsigned)(k>>32); \
  unsigned _mlo = (unsigned)__builtin_amdgcn_mov_dpp((int)_lo, (CTRL), 0xF, 0xF, true); \
  unsigned _mhi = (unsigned)__builtin_amdgcn_mov_dpp((int)_hi, (CTRL), 0xF, 0xF, true); \
  u64 _mk = ((u64)_mhi<<32) | _mlo; \
  k = (_mk > k) ? _mk : k; \
}while(0)

// ======================= MEGA kernel (r10 verbatim, no-spill bounds) =======
// __launch_bounds__(256,1): 1 wave/EU -> VGPR cap 512 -> FPS arrays (196+
// regs) stay in registers instead of spilling to scratch on the serial chain.
template<int PT>
__global__ __launch_bounds__(256, 1) void fps_combo(const float* __restrict__ xyz,
                                                    float* __restrict__ out0,
                                                    const float* __restrict__ pts,
                                                    float* __restrict__ ptsT,
                                                    u32* __restrict__ witem,
                                                    int* __restrict__ idxb_full,
                                                    int* __restrict__ cnt_full,
                                                    int* __restrict__ farIdx){
#pragma clang fp contract(off)
  const int bid = blockIdx.x;
  const int t = threadIdx.x;

  if(bid >= 8){
    if(bid < 8 + NBALLBLK){
      const int row = (bid - 8)*4 + (t>>6);
      const int lane = t & 63;
      const int b = row >> 10;
      const int nc = row & 1023;
      const float* xb = xyz + b*3*NPT;
      const float s0 = xb[nc], s1 = xb[NPT+nc], s2 = xb[2*NPT+nc];
      const float ss = sq3(s0,s1,s2);
      int base = 0;
      int* rowp = idxb_full + row*NS;
      for(int chk=0; chk<16 && base<NS; ++chk){
        const int n = chk*64 + lane;
        float d0 = xb[n], d1 = xb[NPT+n], d2 = xb[2*NPT+n];
        float dd = sq3(d0,d1,d2);
        float p  = radd(radd(rmul(s0,d0), rmul(s1,d1)), rmul(s2,d2));
        float sqr = radd(radd(rmul(-2.0f,p), ss), dd);
        bool inc = !(sqr > RAD2);
        u64 mask = __ballot(inc);
        if(inc){
          int slot = base + __popcll(mask & ((1ull<<lane)-1ull));
          if(slot < NS) rowp[slot] = n;
        }
        base += __popcll(mask);
      }
      if(lane==0) cnt_full[row] = (base < NS) ? base : NS;
    } else {
      const int gid = (bid - 8 - NBALLBLK)*256 + t;
      if(gid < NTILE_MAX*TSLOT) witem[gid] = 0xFFFFFFFFu;
      if constexpr(PT){
        const int w = gid >> 6, ln = gid & 63;
        if(w < 48*16){
          const int b3 = w >> 4, n0 = (w & 15) << 6;
          const float* src = pts + (((size_t)b3*64 + ln) << 10);
          float* dst = ptsT + (((size_t)b3*1024 + n0) << 6) + ln;
          #pragma unroll 4
          for(int i=0;i<64;i++) dst[(size_t)i << 6] = src[n0 + i];
        }
      }
    }
    return;
  }

  // ---- FPS: 2 batches per wave ----
  __shared__ float4 plds[2048];
  if(t >= 64) return;
  __builtin_amdgcn_s_setprio(3);
  const int lane = t;
  const int half = lane >> 5;
  const int hl   = lane & 31;
  const int b    = 2*bid + half;
  const float* xb = xyz + b*3*NPT;

  v2f px2[16], py2[16], pz2[16], dist2[16];
  u32 loj[32];
  #pragma unroll
  for(int i=0;i<16;i++){
    const int n0 = 64*i + hl, n1 = n0 + 32;
    float x0v = xb[n0],        x1v = xb[n1];
    float y0v = xb[NPT+n0],    y1v = xb[NPT+n1];
    float z0v = xb[2*NPT+n0],  z1v = xb[2*NPT+n1];
    px2[i].x = x0v; px2[i].y = x1v;
    py2[i].x = y0v; py2[i].y = y1v;
    pz2[i].x = z0v; pz2[i].y = z1v;
    loj[2*i]   = 1023u - (u32)n0;
    loj[2*i+1] = 1023u - (u32)n1;
    plds[(half<<10) + n0] = make_float4(x0v, y0v, z0v, 0.f);
    plds[(half<<10) + n1] = make_float4(x1v, y1v, z1v, 0.f);
  }
  float sx=0.f, sy=0.f, sz=0.f;
  #pragma unroll
  for(int i=0;i<16;i++){
    sx += px2[i].x; sx += px2[i].y;
    sy += py2[i].x; sy += py2[i].y;
    sz += pz2[i].x; sz += pz2[i].y;
  }
  sx = half_sum32(sx); sy = half_sum32(sy); sz = half_sum32(sz);
  const float cx = sx/1024.f, cy = sy/1024.f, cz = sz/1024.f;
  {
    v2f cx2; cx2.x=cx; cx2.y=cx;
    v2f cy2; cy2.x=cy; cy2.y=cy;
    v2f cz2; cz2.x=cz; cz2.y=cz;
    #pragma unroll
    for(int i=0;i<16;i++){
      v2f dx = px2[i]-cx2, dy = py2[i]-cy2, dz = pz2[i]-cz2;
      v2f m1 = dx*dx, m2 = dy*dy, a1 = m1+m2, m3 = dz*dz, s2 = a1+m3;
      dist2[i].x = fminf(1e10f, s2.x);
      dist2[i].y = fminf(1e10f, s2.y);
    }
  }
  auto reduce2 = [&](int& fA, int& fB){
    u64 kk[16];
    #pragma unroll
    for(int i=0;i<16;i++){
      float a = dist2[i].x, bb = dist2[i].y;
      bool tk = bb > a;                       // tie -> left (lower n)
      float dw = tk ? bb : a;
      u32   lw = tk ? loj[2*i+1] : loj[2*i];
      kk[i] = ((u64)__float_as_uint(dw)<<32) | lw;
    }
    #pragma unroll
    for(int i=0;i<8;i++){ u64 l=kk[2*i], r=kk[2*i+1]; kk[i] = (r>l)?r:l; }
    #pragma unroll
    for(int i=0;i<4;i++){ u64 l=kk[2*i], r=kk[2*i+1]; kk[i] = (r>l)?r:l; }
    #pragma unroll
    for(int i=0;i<2;i++){ u64 l=kk[2*i], r=kk[2*i+1]; kk[i] = (r>l)?r:l; }
    u64 k = (kk[1]>kk[0]) ? kk[1] : kk[0];
    DPPK(0xB1); DPPK(0x4E); DPPK(0x124); DPPK(0x128); DPPK(0x142);
    unsigned lo = (unsigned)k;
    fA = 1023 - __builtin_amdgcn_readlane((int)lo, 31);
    fB = 1023 - __builtin_amdgcn_readlane((int)lo, 63);
  };

  __asm__ volatile("s_waitcnt lgkmcnt(0)" ::: "memory");
  int farA, farB;
  reduce2(farA, farB);
  for(int it=0; it<NP; ++it){
    const int farv = (lane & 32) ? farB : farA;
    const float4 qv = plds[(half<<10) + farv];
    if(hl == 0){
      out0[(b*3+0)*NP + it] = qv.x;
      out0[(b*3+1)*NP + it] = qv.y;
      out0[(b*3+2)*NP + it] = qv.z;
      farIdx[b*NP + it] = farv;
    }
    v2f qx2; qx2.x=qv.x; qx2.y=qv.x;
    v2f qy2; qy2.x=qv.y; qy2.y=qv.y;
    v2f qz2; qz2.x=qv.z; qz2.y=qv.z;
    #pragma unroll
    for(int i=0;i<16;i++){
      v2f dx = px2[i]-qx2, dy = py2[i]-qy2, dz = pz2[i]-qz2;
      v2f m1 = dx*dx, m2 = dy*dy, a1 = m1+m2, m3 = dz*dz, s2 = a1+m3;
      dist2[i].x = fminf(dist2[i].x, s2.x);
      dist2[i].y = fminf(dist2[i].y, s2.y);
    }
    reduce2(farA, farB);
  }
}

// ======================= pack (r10 verbatim) =======================
__global__ __launch_bounds__(1024) void pack_kernel(const int* __restrict__ farIdx,
                                                    const int* __restrict__ cnt_full,
                                                    const int* __restrict__ idxb_full,
                                                    u32* __restrict__ witem,
                                                    int* __restrict__ ntile_dev,
                                                    int* __restrict__ cntb){
  const int t = threadIdx.x;
  const int lane = t & 63;
  const int wv = t >> 6;
  int c[8]; int rowid[8]; int s0 = 0;
  #pragma unroll
  for(int i=0;i<8;i++){
    const int g = t*8+i;
    const int far = farIdx[g];
    rowid[i] = ((g>>9)<<10) + far;
    c[i] = cnt_full[rowid[i]];
    cntb[g] = c[i];
    s0 += c[i];
  }
  int pre = s0;
  #pragma unroll
  for(int d=1; d<64; d<<=1){
    int v = __shfl_up(pre, d, 64);
    if(lane >= d) pre += v;
  }
  __shared__ int wsum[16];
  if(lane==63) wsum[wv] = pre;
  __syncthreads();
  int wo = 0;
  #pragma unroll
  for(int w=0;w<16;w++) if(w < wv) wo += wsum[w];
  int m = wo + pre - s0;
  if(t==1023) *ntile_dev = (wo + pre + TCAP - 1) / TCAP;
  #pragma unroll
  for(int i=0;i<8;i++){
    const int g = t*8+i; const int cc = c[i];
    const int tile = m / TCAP; const int slot = m - TCAP*tile;
    const int* rp = idxb_full + rowid[i]*NS;
    for(int j=0;j<cc;j++){
      witem[tile*TSLOT + slot + j] = (u32)((g<<15) | (j<<10) | rp[j]);
    }
    m += cc;
  }
}

// ======================= Fused MLP passes (r10 + pass3 skip01) =============
template<int DEPTH, int PT>
__global__ __launch_bounds__(384) void pass_kernel(
  const float* __restrict__ xyz, const float* __restrict__ ptsrc,
  const float* __restrict__ W0, const float* __restrict__ W1, const float* __restrict__ W2,
  const float* __restrict__ out0, const u32* __restrict__ witem,
  const int* __restrict__ cntb, const int* __restrict__ ntile_dev,
  const float* __restrict__ inv1, const float* __restrict__ inv2,
  float* __restrict__ part, float* __restrict__ out1,
  int cache_tiles, float* __restrict__ cacheA, float* __restrict__ cacheB)
{
  const int t = threadIdx.x;
  const int c3 = t >> 7;
  const int r  = t & 127;
  const int lane = t & 63;
  const int wv = t >> 6;
  const int bi = blockIdx.x;

  if(bi >= *ntile_dev) return;
  const bool use_cache = (bi < cache_tiles);
  float* cslotA = cacheA + ((size_t)bi*TSLOT + r)*192 + (size_t)c3*64;
  float* cslotB = cacheB + ((size_t)bi*TSLOT + r)*192 + (size_t)c3*64;

  __shared__ float sq[3][128][17];
  __shared__ float wstat[6][128];
  for(int i=t; i<6*128; i+=384) (&wstat[0][0])[i] = 0.f;
  __syncthreads();

  const u32 w = witem[bi*TSLOT + r];
  const bool valid = (w != 0xFFFFFFFFu);
  const int bs = valid ? (int)(w >> 15) : 0;
  const int j  = valid ? (int)((w >> 10) & 31) : 1;
  const int n  = valid ? (int)(w & 1023) : 0;
  const int b = bs >> 9;
  const int s = bs & 511;
  const int b3 = b*3 + c3;
  const int cv = cntb[bs];
  const float wgt = valid ? ((j==0) ? (float)(33 - cv) : 1.0f) : 0.0f;

  float acc2[64];                       // layer-1 raw accumulators
  const bool skip01 = (DEPTH == 3) && use_cache;

  if(!skip01){
    // ---- layer 0: recompute or cacheA ----
    float acc64[64];
    if(DEPTH >= 2 && use_cache){
      #pragma unroll
      for(int q=0;q<16;q++){
        float4 v = ((const float4*)cslotA)[q];
        acc64[4*q]=v.x; acc64[4*q+1]=v.y; acc64[4*q+2]=v.z; acc64[4*q+3]=v.w;
      }
    } else {
      const float gx = xyz[b3*NPT + n];
      const float cx = out0[b3*NP + s];
      float x0[66];
      x0[0] = gx - cx;
      x0[1] = gx;
      if constexpr(PT){
        const float4* pr4 = reinterpret_cast<const float4*>(ptsrc + (((size_t)b3<<10) + (size_t)n)*DF);
        #pragma unroll
        for(int q=0;q<16;q++){
          float4 v = pr4[q];
          x0[2+4*q] = v.x; x0[3+4*q] = v.y; x0[4+4*q] = v.z; x0[5+4*q] = v.w;
        }
      } else {
        const float* pr = ptsrc + ((size_t)b3*DF)*NPT + n;
        #pragma unroll
        for(int c=0;c<DF;c++) x0[2+c] = pr[(size_t)c*NPT];
      }
      #pragma unroll
      for(int ch=0; ch<4; ++ch){
        #pragma unroll
        for(int oo=0;oo<16;oo++){
          const int o = ch*16+oo;
          float a = 0.f;
          #pragma unroll
          for(int c=0;c<66;c++) a = fmaf(W0[o*66+c], x0[c], a);
          acc64[o] = a;
        }
      }
      if(DEPTH == 1 && use_cache){
        #pragma unroll
        for(int q=0;q<16;q++){
          float4 v; v.x=acc64[4*q]; v.y=acc64[4*q+1]; v.z=acc64[4*q+2]; v.w=acc64[4*q+3];
          ((float4*)cslotA)[q] = v;
        }
      }
    }

    if constexpr(DEPTH == 1){
      #pragma unroll
      for(int o=0;o<64;o++){
        float v = wave_sum64(acc64[o]*acc64[o]*wgt);
        if(lane==0) wstat[wv][o] += v;
      }
      __syncthreads();
      if(t < 64){
        float sv = 0.f;
        #pragma unroll
        for(int wq=0;wq<6;wq++) sv += wstat[wq][t];
        part[bi*64 + t] = sv;
      }
      return;
    }

    // ---- qbn1 + qrelu -> y1 ----
    float y1[64];
    #pragma unroll
    for(int ch=0; ch<4; ++ch){
      float xp16[16];
      #pragma unroll
      for(int oo=0;oo<16;oo++){
        const int o = ch*16+oo;
        float xp = acc64[o] * inv1[o];
        xp16[oo] = xp;
        sq[c3][r][oo] = xp*xp;
      }
      __syncthreads();
      #pragma unroll
      for(int oo=0;oo<16;oo++){
        float m2 = (sq[0][r][oo] + sq[1][r][oo]) + sq[2][r][oo];
        float mod = sqrtf(m2);
        float cf = (mod >= 1.f) ? 1.f : mod;
        y1[ch*16+oo] = cf * xp16[oo];
      }
      __syncthreads();
    }

    // ---- layer 1 ----
    #pragma unroll
    for(int ch=0; ch<4; ++ch){
      #pragma unroll
      for(int oo=0;oo<16;oo++){
        const int o = ch*16+oo;
        float a = 0.f;
        #pragma unroll
        for(int c=0;c<64;c++) a = fmaf(W1[o*64+c], y1[c], a);
        acc2[o] = a;
      }
    }
    if(DEPTH == 2 && use_cache){
      #pragma unroll
      for(int q=0;q<16;q++){
        float4 v; v.x=acc2[4*q]; v.y=acc2[4*q+1]; v.z=acc2[4*q+2]; v.w=acc2[4*q+3];
        ((float4*)cslotB)[q] = v;
      }
    }
  } else {
    // DEPTH==3 + cache: acc2 straight from cacheB (layer0/qbn1/GEMM1 skipped;
    // stored floats are bit-identical to the recomputed ones)
    #pragma unroll
    for(int q=0;q<16;q++){
      float4 v = ((const float4*)cslotB)[q];
      acc2[4*q]=v.x; acc2[4*q+1]=v.y; acc2[4*q+2]=v.z; acc2[4*q+3]=v.w;
    }
  }

  if constexpr(DEPTH == 2){
    #pragma unroll
    for(int o=0;o<64;o++){
      float v = wave_sum64(acc2[o]*acc2[o]*wgt);
      if(lane==0) wstat[wv][o] += v;
    }
    __syncthreads();
    if(t < 64){
      float sv = 0.f;
      #pragma unroll
      for(int wq=0;wq<6;wq++) sv += wstat[wq][t];
      part[bi*64 + t] = sv;
    }
    return;
  }

  if constexpr(DEPTH == 3){
    // ---- qbn2 + qrelu -> y2 ----
    float y2[64];
    #pragma unroll
    for(int ch=0; ch<4; ++ch){
      float xp16[16];
      #pragma unroll
      for(int oo=0;oo<16;oo++){
        const int o = ch*16+oo;
        float xp = acc2[o] * inv2[o];
        xp16[oo] = xp;
        sq[c3][r][oo] = xp*xp;
      }
      __syncthreads();
      #pragma unroll
      for(int oo=0;oo<16;oo++){
        float m2 = (sq[0][r][oo] + sq[1][r][oo]) + sq[2][r][oo];
        float mod = sqrtf(m2);
        float cf = (mod >= 1.f) ? 1.f : mod;
        y2[ch*16+oo] = cf * xp16[oo];
      }
      __syncthreads();
    }

    // ---- layer 2 + per-group serial argmax + stats3 ----
    #pragma unroll
    for(int ch=0; ch<8; ++ch){
      #pragma unroll
      for(int oo=0;oo<16;oo++){
        const int o = ch*16+oo;
        float a = 0.f;
        #pragma unroll
        for(int c=0;c<64;c++) a = fmaf(W2[o*64+c], y2[c], a);
        sq[c3][r][oo] = a;          // RAW x3
      }
      __syncthreads();
      if(c3 == 0){
        #pragma unroll
        for(int oo=0;oo<16;oo++){
          float a0 = sq[0][r][oo], a1 = sq[1][r][oo], a2 = sq[2][r][oo];
          float m2 = radd(radd(rmul(a0,a0), rmul(a1,a1)), rmul(a2,a2));
          float v = wave_sum64(m2*wgt);
          if(lane==0) wstat[wv][ch*16+oo] += v;
          if(valid && j==0){
            float bvv = m2; int bjj = 0;
            for(int jj=1; jj<cv; ++jj){
              float c0 = sq[0][r+jj][oo], c1 = sq[1][r+jj][oo], c2 = sq[2][r+jj][oo];
              float mm = radd(radd(rmul(c0,c0), rmul(c1,c1)), rmul(c2,c2));
              if(mm > bvv){ bvv = mm; bjj = jj; }
            }
            const int o = ch*16+oo;
            #pragma unroll
            for(int cc=0;cc<3;cc++){
              out1[(((size_t)(3*b+cc))*128 + o)*NP + s] = sq[cc][r+bjj][oo];
            }
          }
        }
      }
      __syncthreads();
    }
    if(t < 128){
      part[bi*128 + t] = wstat[0][t] + wstat[1][t];
    }
  }
}

// ======================= stats finalize (r10 verbatim) =======================
__global__ __launch_bounds__(256) void fin_kernel(const float* __restrict__ part,
                                                  const int* __restrict__ ntile_dev, int nch,
                                                  float* __restrict__ inv){
  const int o = blockIdx.x;
  const int t = threadIdx.x;
  const int nblk = *ntile_dev;
  float sum = 0.f;
  for(int i=t; i<nblk; i+=256) sum += part[(size_t)i*nch + o];
  sum = wave_sum64(sum);
  __shared__ float red[4];
  if((t&63)==0) red[t>>6] = sum;
  __syncthreads();
  if(t==0){
    float tot = (red[0]+red[1])+(red[2]+red[3]);
    inv[o] = 1.0f / sqrtf(tot/CNTF + EPSQ);
  }
}

// ======================= fin3 + final qbn+qrelu fused (r10 verbatim) ========
__global__ __launch_bounds__(256) void fin3_scale(const float* __restrict__ part3,
                                                  const int* __restrict__ ntile_dev,
                                                  float* __restrict__ out){
  const int o = blockIdx.x;
  const int t = threadIdx.x;
  const int nblk = *ntile_dev;
  float sum = 0.f;
  for(int i=t; i<nblk; i+=256) sum += part3[(size_t)i*128 + o];
  sum = wave_sum64(sum);
  __shared__ float red[4];
  __shared__ float sinv;
  if((t&63)==0) red[t>>6] = sum;
  __syncthreads();
  if(t==0){
    float tot = (red[0]+red[1])+(red[2]+red[3]);
    sinv = 1.0f / sqrtf(tot/CNTF + EPSQ);
  }
  __syncthreads();
  const float iv = sinv;
  float* base = out + NB*3*NP;
  const size_t str = (size_t)128*NP;
  for(int idx=t; idx<NB*NP; idx+=256){
    const int b = idx >> 9, s = idx & 511;
    size_t i0 = ((size_t)(b*3)*128 + o)*NP + s;
    float a0 = base[i0] * iv;
    float a1 = base[i0+str] * iv;
    float a2 = base[i0+2*str] * iv;
    float m2 = (a0*a0 + a1*a1) + a2*a2;
    float mod = sqrtf(m2);
    float cf = (mod >= 1.f) ? 1.f : mod;
    base[i0] = cf*a0; base[i0+str] = cf*a1; base[i0+2*str] = cf*a2;
  }
}

// ======================= host (r10 verbatim) =======================
extern "C" void kernel_launch(void* const* d_in, const int* in_sizes, int n_in,
                              void* d_out, int out_size, void* d_ws, size_t ws_size,
                              hipStream_t stream){
  const float* xyz = (const float*)d_in[0];
  const float* pts = (const float*)d_in[1];
  const float* W0  = (const float*)d_in[2];
  const float* W1  = (const float*)d_in[3];
  const float* W2  = (const float*)d_in[4];
  float* out = (float*)d_out;

  char* p = (char*)d_ws;
  auto carve = [&](size_t bytes)->char*{
    char* q = p; p += (bytes + 255) & ~(size_t)255; return q;
  };
  int*   idxb_full = (int*)  carve((size_t)NB*NPT*NS*4);
  int*   cnt_full  = (int*)  carve((size_t)NB*NPT*4);
  int*   farIdx    = (int*)  carve((size_t)NGRP*4);
  int*   cntb      = (int*)  carve((size_t)NGRP*4);
  u32*   witem     = (u32*)  carve((size_t)NTILE_MAX*TSLOT*4);
  int*   ntile_dev = (int*)  carve(256);
  float* part1     = (float*)carve((size_t)NTILE_MAX*64*4);
  float* part2     = (float*)carve((size_t)NTILE_MAX*64*4);
  float* part3     = (float*)carve((size_t)NTILE_MAX*128*4);
  float* inv1      = (float*)carve(64*4);
  float* inv2      = (float*)carve(64*4);
  size_t base_need = (size_t)(p - (char*)d_ws);
  float* ptsT      = (float*)p;
  const size_t pt_bytes = (size_t)48*1024*64*4;
  const bool use_pt = (ws_size >= base_need + pt_bytes + (1u<<20));

  size_t fixed = base_need + (use_pt ? pt_bytes : 0);
  const size_t per_tile = (size_t)TSLOT*192*4*2;
  int cache_tiles = 0;
  if(ws_size > fixed + per_tile)
    cache_tiles = (int)((ws_size - fixed) / per_tile);
  if(cache_tiles > NTILE_MAX) cache_tiles = NTILE_MAX;
  float* cacheA = (float*)((char*)d_ws + fixed);
  float* cacheB = cacheA + (size_t)cache_tiles*TSLOT*192;

  float* out1 = out + NB*3*NP;
  const int nblk = 8 + NBALLBLK + NFILLBLK;

  if(use_pt) fps_combo<1><<<nblk, 256, 0, stream>>>(xyz, out, pts, ptsT, witem, idxb_full, cnt_full, farIdx);
  else       fps_combo<0><<<nblk, 256, 0, stream>>>(xyz, out, pts, nullptr, witem, idxb_full, cnt_full, farIdx);

  pack_kernel<<<1, 1024, 0, stream>>>(farIdx, cnt_full, idxb_full, witem, ntile_dev, cntb);

  if(use_pt){
    pass_kernel<1,1><<<NTILE_MAX, 384, 0, stream>>>(xyz, ptsT, W0, W1, W2, out, witem, cntb, ntile_dev, nullptr, nullptr, part1, nullptr, cache_tiles, cacheA, cacheB);
    fin_kernel<<<64, 256, 0, stream>>>(part1, ntile_dev, 64, inv1);
    pass_kernel<2,1><<<NTILE_MAX, 384, 0, stream>>>(xyz, ptsT, W0, W1, W2, out, witem, cntb, ntile_dev, inv1, nullptr, part2, nullptr, cache_tiles, cacheA, cacheB);
    fin_kernel<<<64, 256, 0, stream>>>(part2, ntile_dev, 64, inv2);
    pass_kernel<3,1><<<NTILE_MAX, 384, 0, stream>>>(xyz, ptsT, W0, W1, W2, out, witem, cntb, ntile_dev, inv1, inv2, part3, out1, cache_tiles, cacheA, cacheB);
  } else {
    pass_kernel<1,0><<<NTILE_MAX, 384, 0, stream>>>(xyz, pts, W0, W1, W2, out, witem, cntb, ntile_dev, nullptr, nullptr, part1, nullptr, cache_tiles, cacheA, cacheB);
    fin_kernel<<<64, 256, 0, stream>>>(part1, ntile_dev, 64, inv1);
    pass_kernel<2,0><<<NTILE_MAX, 384, 0, stream>>>(xyz, pts, W0, W1, W2, out, witem, cntb, ntile_dev, inv1, nullptr, part2, nullptr, cache_tiles, cacheA, cacheB);
    fin_kernel<<<64, 256, 0, stream>>>(part2, ntile_dev, 64, inv2);
    pass_kernel<3,0><<<NTILE_MAX, 384, 0, stream>>>(xyz, pts, W0, W1, W2, out, witem, cntb, ntile_dev, inv1, inv2, part3, out1, cache_tiles, cacheA, cacheB);
  }
  fin3_scale<<<128, 256, 0, stream>>>(part3, ntile_dev, out);
}

// Round 14
// 741.807 us; speedup vs baseline: 4.0647x; 1.0043x over previous
//
#include <hip/hip_runtime.h>

typedef unsigned int u32;
typedef unsigned long long u64;
typedef float v2f __attribute__((ext_vector_type(2)));

#define NB 16
#define NPT 1024
#define NP 512
#define NS 32
#define DF 64
#define RAD2 0.04f
#define EPSQ 1e-5f
#define CNTF 786432.0f   // 48*512*32
#define NGRP 8192        // NB*NP
#define TCAP 96
#define TSLOT 128
#define NTILE_MAX 2731
#define NBALLBLK 4096    // 4096 blocks x 4 waves = 16384 ball rows
#define NFILLBLK 1366

// --- np-matching (contraction-proof) arithmetic -------------------------
__device__ __forceinline__ float rmul(float a, float b){ return __fmul_rn(a,b); }
__device__ __forceinline__ float radd(float a, float b){ return __fadd_rn(a,b); }
__device__ __forceinline__ float sq3(float a, float b, float c){
  return radd(radd(rmul(a,a), rmul(b,b)), rmul(c,c));
}

// opaque register pin: blocks rematerialization-by-reload (value must live
// in a VGPR thereafter). Empty asm -> zero arithmetic effect.
#define PIN(x) asm("" : "+v"(x))

__device__ __forceinline__ float wave_sum64(float v){
  #pragma unroll
  for(int m=1;m<64;m<<=1) v += __shfl_xor(v, m, 64);
  return v;
}
__device__ __forceinline__ float half_sum32(float v){
  #pragma unroll
  for(int m=1;m<32;m<<=1) v += __shfl_xor(v, m, 64);
  return v;
}

// DPP max-combine on u64 key (strict >).
#define DPPK(CTRL) do{ \
  unsigned _lo = (unsigned)k, _hi = (unsigned)(k>>32); \
  unsigned _mlo = (unsigned)__builtin_amdgcn_mov_dpp((int)_lo, (CTRL), 0xF, 0xF, true); \
  unsigned _mhi = (unsigned)__builtin_amdgcn_mov_dpp((int)_hi, (CTRL), 0xF, 0xF, true); \
  u64 _mk = ((u64)_mhi<<32) | _mlo; \
  k = (_mk > k) ? _mk : k; \
}while(0)

// ======================= MEGA kernel =======================
template<int PT>
__global__ __launch_bounds__(256, 1) void fps_combo(const float* __restrict__ xyz,
                                                    float* __restrict__ out0,
                                                    const float* __restrict__ pts,
                                                    float* __restrict__ ptsT,
                                                    u32* __restrict__ witem,
                                                    int* __restrict__ idxb_full,
                                                    int* __restrict__ cnt_full,
                                                    int* __restrict__ farIdx){
#pragma clang fp contract(off)
  const int bid = blockIdx.x;
  const int t = threadIdx.x;

  if(bid >= 8){
    if(bid < 8 + NBALLBLK){
      const int row = (bid - 8)*4 + (t>>6);
      const int lane = t & 63;
      const int b = row >> 10;
      const int nc = row & 1023;
      const float* xb = xyz + b*3*NPT;
      const float s0 = xb[nc], s1 = xb[NPT+nc], s2 = xb[2*NPT+nc];
      const float ss = sq3(s0,s1,s2);
      int base = 0;
      int* rowp = idxb_full + row*NS;
      for(int chk=0; chk<16 && base<NS; ++chk){
        const int n = chk*64 + lane;
        float d0 = xb[n], d1 = xb[NPT+n], d2 = xb[2*NPT+n];
        float dd = sq3(d0,d1,d2);
        float p  = radd(radd(rmul(s0,d0), rmul(s1,d1)), rmul(s2,d2));
        float sqr = radd(radd(rmul(-2.0f,p), ss), dd);
        bool inc = !(sqr > RAD2);
        u64 mask = __ballot(inc);
        if(inc){
          int slot = base + __popcll(mask & ((1ull<<lane)-1ull));
          if(slot < NS) rowp[slot] = n;
        }
        base += __popcll(mask);
      }
      if(lane==0) cnt_full[row] = (base < NS) ? base : NS;
    } else {
      const int gid = (bid - 8 - NBALLBLK)*256 + t;
      if(gid < NTILE_MAX*TSLOT) witem[gid] = 0xFFFFFFFFu;
      if constexpr(PT){
        const int w = gid >> 6, ln = gid & 63;
        if(w < 48*16){
          const int b3 = w >> 4, n0 = (w & 15) << 6;
          const float* src = pts + (((size_t)b3*64 + ln) << 10);
          float* dst = ptsT + (((size_t)b3*1024 + n0) << 6) + ln;
          #pragma unroll 4
          for(int i=0;i<64;i++) dst[(size_t)i << 6] = src[n0 + i];
        }
      }
    }
    return;
  }

  // ---- FPS: 2 batches per wave; coords PINNED into registers ----
  __shared__ float4 plds[2048];
  if(t >= 64) return;
  __builtin_amdgcn_s_setprio(3);
  const int lane = t;
  const int half = lane >> 5;
  const int hl   = lane & 31;
  const int b    = 2*bid + half;
  const float* xb = xyz + b*3*NPT;

  v2f px2[16], py2[16], pz2[16], dist2[16];
  u32 loj[32];
  #pragma unroll
  for(int i=0;i<16;i++){
    const int n0 = 64*i + hl, n1 = n0 + 32;
    float x0v = xb[n0],        x1v = xb[n1];
    float y0v = xb[NPT+n0],    y1v = xb[NPT+n1];
    float z0v = xb[2*NPT+n0],  z1v = xb[2*NPT+n1];
    PIN(x0v); PIN(x1v); PIN(y0v); PIN(y1v); PIN(z0v); PIN(z1v);
    px2[i].x = x0v; px2[i].y = x1v;
    py2[i].x = y0v; py2[i].y = y1v;
    pz2[i].x = z0v; pz2[i].y = z1v;
    loj[2*i]   = 1023u - (u32)n0;
    loj[2*i+1] = 1023u - (u32)n1;
    plds[(half<<10) + n0] = make_float4(x0v, y0v, z0v, 0.f);
    plds[(half<<10) + n1] = make_float4(x1v, y1v, z1v, 0.f);
  }
  float sx=0.f, sy=0.f, sz=0.f;
  #pragma unroll
  for(int i=0;i<16;i++){
    sx += px2[i].x; sx += px2[i].y;
    sy += py2[i].x; sy += py2[i].y;
    sz += pz2[i].x; sz += pz2[i].y;
  }
  sx = half_sum32(sx); sy = half_sum32(sy); sz = half_sum32(sz);
  const float cx = sx/1024.f, cy = sy/1024.f, cz = sz/1024.f;
  {
    v2f cx2; cx2.x=cx; cx2.y=cx;
    v2f cy2; cy2.x=cy; cy2.y=cy;
    v2f cz2; cz2.x=cz; cz2.y=cz;
    #pragma unroll
    for(int i=0;i<16;i++){
      v2f dx = px2[i]-cx2, dy = py2[i]-cy2, dz = pz2[i]-cz2;
      v2f m1 = dx*dx, m2 = dy*dy, a1 = m1+m2, m3 = dz*dz, s2 = a1+m3;
      dist2[i].x = fminf(1e10f, s2.x);
      dist2[i].y = fminf(1e10f, s2.y);
    }
  }
  auto reduce2 = [&](int& fA, int& fB){
    u64 kk[16];
    #pragma unroll
    for(int i=0;i<16;i++){
      float a = dist2[i].x, bb = dist2[i].y;
      bool tk = bb > a;                       // tie -> left (lower n)
      float dw = tk ? bb : a;
      u32   lw = tk ? loj[2*i+1] : loj[2*i];
      kk[i] = ((u64)__float_as_uint(dw)<<32) | lw;
    }
    #pragma unroll
    for(int i=0;i<8;i++){ u64 l=kk[2*i], r=kk[2*i+1]; kk[i] = (r>l)?r:l; }
    #pragma unroll
    for(int i=0;i<4;i++){ u64 l=kk[2*i], r=kk[2*i+1]; kk[i] = (r>l)?r:l; }
    #pragma unroll
    for(int i=0;i<2;i++){ u64 l=kk[2*i], r=kk[2*i+1]; kk[i] = (r>l)?r:l; }
    u64 k = (kk[1]>kk[0]) ? kk[1] : kk[0];
    DPPK(0xB1); DPPK(0x4E); DPPK(0x124); DPPK(0x128); DPPK(0x142);
    unsigned lo = (unsigned)k;
    fA = 1023 - __builtin_amdgcn_readlane((int)lo, 31);
    fB = 1023 - __builtin_amdgcn_readlane((int)lo, 63);
  };

  __asm__ volatile("s_waitcnt lgkmcnt(0)" ::: "memory");
  int farA, farB;
  reduce2(farA, farB);
  for(int it=0; it<NP; ++it){
    const int farv = (lane & 32) ? farB : farA;
    const float4 qv = plds[(half<<10) + farv];
    if(hl == 0){
      out0[(b*3+0)*NP + it] = qv.x;
      out0[(b*3+1)*NP + it] = qv.y;
      out0[(b*3+2)*NP + it] = qv.z;
      farIdx[b*NP + it] = farv;
    }
    v2f qx2; qx2.x=qv.x; qx2.y=qv.x;
    v2f qy2; qy2.x=qv.y; qy2.y=qv.y;
    v2f qz2; qz2.x=qv.z; qz2.y=qv.z;
    #pragma unroll
    for(int i=0;i<16;i++){
      v2f dx = px2[i]-qx2, dy = py2[i]-qy2, dz = pz2[i]-qz2;
      v2f m1 = dx*dx, m2 = dy*dy, a1 = m1+m2, m3 = dz*dz, s2 = a1+m3;
      dist2[i].x = fminf(dist2[i].x, s2.x);
      dist2[i].y = fminf(dist2[i].y, s2.y);
    }
    reduce2(farA, farB);
  }
}

// ======================= pack (r10 verbatim) =======================
__global__ __launch_bounds__(1024) void pack_kernel(const int* __restrict__ farIdx,
                                                    const int* __restrict__ cnt_full,
                                                    const int* __restrict__ idxb_full,
                                                    u32* __restrict__ witem,
                                                    int* __restrict__ ntile_dev,
                                                    int* __restrict__ cntb){
  const int t = threadIdx.x;
  const int lane = t & 63;
  const int wv = t >> 6;
  int c[8]; int rowid[8]; int s0 = 0;
  #pragma unroll
  for(int i=0;i<8;i++){
    const int g = t*8+i;
    const int far = farIdx[g];
    rowid[i] = ((g>>9)<<10) + far;
    c[i] = cnt_full[rowid[i]];
    cntb[g] = c[i];
    s0 += c[i];
  }
  int pre = s0;
  #pragma unroll
  for(int d=1; d<64; d<<=1){
    int v = __shfl_up(pre, d, 64);
    if(lane >= d) pre += v;
  }
  __shared__ int wsum[16];
  if(lane==63) wsum[wv] = pre;
  __syncthreads();
  int wo = 0;
  #pragma unroll
  for(int w=0;w<16;w++) if(w < wv) wo += wsum[w];
  int m = wo + pre - s0;
  if(t==1023) *ntile_dev = (wo + pre + TCAP - 1) / TCAP;
  #pragma unroll
  for(int i=0;i<8;i++){
    const int g = t*8+i; const int cc = c[i];
    const int tile = m / TCAP; const int slot = m - TCAP*tile;
    const int* rp = idxb_full + rowid[i]*NS;
    for(int j=0;j<cc;j++){
      witem[tile*TSLOT + slot + j] = (u32)((g<<15) | (j<<10) | rp[j]);
    }
    m += cc;
  }
}

// ======================= Fused MLP passes (r13 verbatim) ===================
template<int DEPTH, int PT>
__global__ __launch_bounds__(384) void pass_kernel(
  const float* __restrict__ xyz, const float* __restrict__ ptsrc,
  const float* __restrict__ W0, const float* __restrict__ W1, const float* __restrict__ W2,
  const float* __restrict__ out0, const u32* __restrict__ witem,
  const int* __restrict__ cntb, const int* __restrict__ ntile_dev,
  const float* __restrict__ inv1, const float* __restrict__ inv2,
  float* __restrict__ part, float* __restrict__ out1,
  int cache_tiles, float* __restrict__ cacheA, float* __restrict__ cacheB)
{
  const int t = threadIdx.x;
  const int c3 = t >> 7;
  const int r  = t & 127;
  const int lane = t & 63;
  const int wv = t >> 6;
  const int bi = blockIdx.x;

  if(bi >= *ntile_dev) return;
  const bool use_cache = (bi < cache_tiles);
  float* cslotA = cacheA + ((size_t)bi*TSLOT + r)*192 + (size_t)c3*64;
  float* cslotB = cacheB + ((size_t)bi*TSLOT + r)*192 + (size_t)c3*64;

  __shared__ float sq[3][128][17];
  __shared__ float wstat[6][128];
  for(int i=t; i<6*128; i+=384) (&wstat[0][0])[i] = 0.f;
  __syncthreads();

  const u32 w = witem[bi*TSLOT + r];
  const bool valid = (w != 0xFFFFFFFFu);
  const int bs = valid ? (int)(w >> 15) : 0;
  const int j  = valid ? (int)((w >> 10) & 31) : 1;
  const int n  = valid ? (int)(w & 1023) : 0;
  const int b = bs >> 9;
  const int s = bs & 511;
  const int b3 = b*3 + c3;
  const int cv = cntb[bs];
  const float wgt = valid ? ((j==0) ? (float)(33 - cv) : 1.0f) : 0.0f;

  float acc2[64];
  const bool skip01 = (DEPTH == 3) && use_cache;

  if(!skip01){
    float acc64[64];
    if(DEPTH >= 2 && use_cache){
      #pragma unroll
      for(int q=0;q<16;q++){
        float4 v = ((const float4*)cslotA)[q];
        acc64[4*q]=v.x; acc64[4*q+1]=v.y; acc64[4*q+2]=v.z; acc64[4*q+3]=v.w;
      }
    } else {
      const float gx = xyz[b3*NPT + n];
      const float cx = out0[b3*NP + s];
      float x0[66];
      x0[0] = gx - cx;
      x0[1] = gx;
      if constexpr(PT){
        const float4* pr4 = reinterpret_cast<const float4*>(ptsrc + (((size_t)b3<<10) + (size_t)n)*DF);
        #pragma unroll
        for(int q=0;q<16;q++){
          float4 v = pr4[q];
          x0[2+4*q] = v.x; x0[3+4*q] = v.y; x0[4+4*q] = v.z; x0[5+4*q] = v.w;
        }
      } else {
        const float* pr = ptsrc + ((size_t)b3*DF)*NPT + n;
        #pragma unroll
        for(int c=0;c<DF;c++) x0[2+c] = pr[(size_t)c*NPT];
      }
      #pragma unroll
      for(int ch=0; ch<4; ++ch){
        #pragma unroll
        for(int oo=0;oo<16;oo++){
          const int o = ch*16+oo;
          float a = 0.f;
          #pragma unroll
          for(int c=0;c<66;c++) a = fmaf(W0[o*66+c], x0[c], a);
          acc64[o] = a;
        }
      }
      if(DEPTH == 1 && use_cache){
        #pragma unroll
        for(int q=0;q<16;q++){
          float4 v; v.x=acc64[4*q]; v.y=acc64[4*q+1]; v.z=acc64[4*q+2]; v.w=acc64[4*q+3];
          ((float4*)cslotA)[q] = v;
        }
      }
    }

    if constexpr(DEPTH == 1){
      #pragma unroll
      for(int o=0;o<64;o++){
        float v = wave_sum64(acc64[o]*acc64[o]*wgt);
        if(lane==0) wstat[wv][o] += v;
      }
      __syncthreads();
      if(t < 64){
        float sv = 0.f;
        #pragma unroll
        for(int wq=0;wq<6;wq++) sv += wstat[wq][t];
        part[bi*64 + t] = sv;
      }
      return;
    }

    // ---- qbn1 + qrelu -> y1 ----
    float y1[64];
    #pragma unroll
    for(int ch=0; ch<4; ++ch){
      float xp16[16];
      #pragma unroll
      for(int oo=0;oo<16;oo++){
        const int o = ch*16+oo;
        float xp = acc64[o] * inv1[o];
        xp16[oo] = xp;
        sq[c3][r][oo] = xp*xp;
      }
      __syncthreads();
      #pragma unroll
      for(int oo=0;oo<16;oo++){
        float m2 = (sq[0][r][oo] + sq[1][r][oo]) + sq[2][r][oo];
        float mod = sqrtf(m2);
        float cf = (mod >= 1.f) ? 1.f : mod;
        y1[ch*16+oo] = cf * xp16[oo];
      }
      __syncthreads();
    }

    // ---- layer 1 ----
    #pragma unroll
    for(int ch=0; ch<4; ++ch){
      #pragma unroll
      for(int oo=0;oo<16;oo++){
        const int o = ch*16+oo;
        float a = 0.f;
        #pragma unroll
        for(int c=0;c<64;c++) a = fmaf(W1[o*64+c], y1[c], a);
        acc2[o] = a;
      }
    }
    if(DEPTH == 2 && use_cache){
      #pragma unroll
      for(int q=0;q<16;q++){
        float4 v; v.x=acc2[4*q]; v.y=acc2[4*q+1]; v.z=acc2[4*q+2]; v.w=acc2[4*q+3];
        ((float4*)cslotB)[q] = v;
      }
    }
  } else {
    #pragma unroll
    for(int q=0;q<16;q++){
      float4 v = ((const float4*)cslotB)[q];
      acc2[4*q]=v.x; acc2[4*q+1]=v.y; acc2[4*q+2]=v.z; acc2[4*q+3]=v.w;
    }
  }

  if constexpr(DEPTH == 2){
    #pragma unroll
    for(int o=0;o<64;o++){
      float v = wave_sum64(acc2[o]*acc2[o]*wgt);
      if(lane==0) wstat[wv][o] += v;
    }
    __syncthreads();
    if(t < 64){
      float sv = 0.f;
      #pragma unroll
      for(int wq=0;wq<6;wq++) sv += wstat[wq][t];
      part[bi*64 + t] = sv;
    }
    return;
  }

  if constexpr(DEPTH == 3){
    // ---- qbn2 + qrelu -> y2 ----
    float y2[64];
    #pragma unroll
    for(int ch=0; ch<4; ++ch){
      float xp16[16];
      #pragma unroll
      for(int oo=0;oo<16;oo++){
        const int o = ch*16+oo;
        float xp = acc2[o] * inv2[o];
        xp16[oo] = xp;
        sq[c3][r][oo] = xp*xp;
      }
      __syncthreads();
      #pragma unroll
      for(int oo=0;oo<16;oo++){
        float m2 = (sq[0][r][oo] + sq[1][r][oo]) + sq[2][r][oo];
        float mod = sqrtf(m2);
        float cf = (mod >= 1.f) ? 1.f : mod;
        y2[ch*16+oo] = cf * xp16[oo];
      }
      __syncthreads();
    }

    // ---- layer 2 + per-group serial argmax + stats3 ----
    #pragma unroll
    for(int ch=0; ch<8; ++ch){
      #pragma unroll
      for(int oo=0;oo<16;oo++){
        const int o = ch*16+oo;
        float a = 0.f;
        #pragma unroll
        for(int c=0;c<64;c++) a = fmaf(W2[o*64+c], y2[c], a);
        sq[c3][r][oo] = a;          // RAW x3
      }
      __syncthreads();
      if(c3 == 0){
        #pragma unroll
        for(int oo=0;oo<16;oo++){
          float a0 = sq[0][r][oo], a1 = sq[1][r][oo], a2 = sq[2][r][oo];
          float m2 = radd(radd(rmul(a0,a0), rmul(a1,a1)), rmul(a2,a2));
          float v = wave_sum64(m2*wgt);
          if(lane==0) wstat[wv][ch*16+oo] += v;
          if(valid && j==0){
            float bvv = m2; int bjj = 0;
            for(int jj=1; jj<cv; ++jj){
              float c0 = sq[0][r+jj][oo], c1 = sq[1][r+jj][oo], c2 = sq[2][r+jj][oo];
              float mm = radd(radd(rmul(c0,c0), rmul(c1,c1)), rmul(c2,c2));
              if(mm > bvv){ bvv = mm; bjj = jj; }
            }
            const int o = ch*16+oo;
            #pragma unroll
            for(int cc=0;cc<3;cc++){
              out1[(((size_t)(3*b+cc))*128 + o)*NP + s] = sq[cc][r+bjj][oo];
            }
          }
        }
      }
      __syncthreads();
    }
    if(t < 128){
      part[bi*128 + t] = wstat[0][t] + wstat[1][t];
    }
  }
}

// ======================= stats finalize (r10 verbatim) =======================
__global__ __launch_bounds__(256) void fin_kernel(const float* __restrict__ part,
                                                  const int* __restrict__ ntile_dev, int nch,
                                                  float* __restrict__ inv){
  const int o = blockIdx.x;
  const int t = threadIdx.x;
  const int nblk = *ntile_dev;
  float sum = 0.f;
  for(int i=t; i<nblk; i+=256) sum += part[(size_t)i*nch + o];
  sum = wave_sum64(sum);
  __shared__ float red[4];
  if((t&63)==0) red[t>>6] = sum;
  __syncthreads();
  if(t==0){
    float tot = (red[0]+red[1])+(red[2]+red[3]);
    inv[o] = 1.0f / sqrtf(tot/CNTF + EPSQ);
  }
}

// ======================= fin3 + final qbn+qrelu fused (r10 verbatim) ========
__global__ __launch_bounds__(256) void fin3_scale(const float* __restrict__ part3,
                                                  const int* __restrict__ ntile_dev,
                                                  float* __restrict__ out){
  const int o = blockIdx.x;
  const int t = threadIdx.x;
  const int nblk = *ntile_dev;
  float sum = 0.f;
  for(int i=t; i<nblk; i+=256) sum += part3[(size_t)i*128 + o];
  sum = wave_sum64(sum);
  __shared__ float red[4];
  __shared__ float sinv;
  if((t&63)==0) red[t>>6] = sum;
  __syncthreads();
  if(t==0){
    float tot = (red[0]+red[1])+(red[2]+red[3]);
    sinv = 1.0f / sqrtf(tot/CNTF + EPSQ);
  }
  __syncthreads();
  const float iv = sinv;
  float* base = out + NB*3*NP;
  const size_t str = (size_t)128*NP;
  for(int idx=t; idx<NB*NP; idx+=256){
    const int b = idx >> 9, s = idx & 511;
    size_t i0 = ((size_t)(b*3)*128 + o)*NP + s;
    float a0 = base[i0] * iv;
    float a1 = base[i0+str] * iv;
    float a2 = base[i0+2*str] * iv;
    float m2 = (a0*a0 + a1*a1) + a2*a2;
    float mod = sqrtf(m2);
    float cf = (mod >= 1.f) ? 1.f : mod;
    base[i0] = cf*a0; base[i0+str] = cf*a1; base[i0+2*str] = cf*a2;
  }
}

// ======================= host (r13 verbatim) =======================
extern "C" void kernel_launch(void* const* d_in, const int* in_sizes, int n_in,
                              void* d_out, int out_size, void* d_ws, size_t ws_size,
                              hipStream_t stream){
  const float* xyz = (const float*)d_in[0];
  const float* pts = (const float*)d_in[1];
  const float* W0  = (const float*)d_in[2];
  const float* W1  = (const float*)d_in[3];
  const float* W2  = (const float*)d_in[4];
  float* out = (float*)d_out;

  char* p = (char*)d_ws;
  auto carve = [&](size_t bytes)->char*{
    char* q = p; p += (bytes + 255) & ~(size_t)255; return q;
  };
  int*   idxb_full = (int*)  carve((size_t)NB*NPT*NS*4);
  int*   cnt_full  = (int*)  carve((size_t)NB*NPT*4);
  int*   farIdx    = (int*)  carve((size_t)NGRP*4);
  int*   cntb      = (int*)  carve((size_t)NGRP*4);
  u32*   witem     = (u32*)  carve((size_t)NTILE_MAX*TSLOT*4);
  int*   ntile_dev = (int*)  carve(256);
  float* part1     = (float*)carve((size_t)NTILE_MAX*64*4);
  float* part2     = (float*)carve((size_t)NTILE_MAX*64*4);
  float* part3     = (float*)carve((size_t)NTILE_MAX*128*4);
  float* inv1      = (float*)carve(64*4);
  float* inv2      = (float*)carve(64*4);
  size_t base_need = (size_t)(p - (char*)d_ws);
  float* ptsT      = (float*)p;
  const size_t pt_bytes = (size_t)48*1024*64*4;
  const bool use_pt = (ws_size >= base_need + pt_bytes + (1u<<20));

  size_t fixed = base_need + (use_pt ? pt_bytes : 0);
  const size_t per_tile = (size_t)TSLOT*192*4*2;
  int cache_tiles = 0;
  if(ws_size > fixed + per_tile)
    cache_tiles = (int)((ws_size - fixed) / per_tile);
  if(cache_tiles > NTILE_MAX) cache_tiles = NTILE_MAX;
  float* cacheA = (float*)((char*)d_ws + fixed);
  float* cacheB = cacheA + (size_t)cache_tiles*TSLOT*192;

  float* out1 = out + NB*3*NP;
  const int nblk = 8 + NBALLBLK + NFILLBLK;

  if(use_pt) fps_combo<1><<<nblk, 256, 0, stream>>>(xyz, out, pts, ptsT, witem, idxb_full, cnt_full, farIdx);
  else       fps_combo<0><<<nblk, 256, 0, stream>>>(xyz, out, pts, nullptr, witem, idxb_full, cnt_full, farIdx);

  pack_kernel<<<1, 1024, 0, stream>>>(farIdx, cnt_full, idxb_full, witem, ntile_dev, cntb);

  if(use_pt){
    pass_kernel<1,1><<<NTILE_MAX, 384, 0, stream>>>(xyz, ptsT, W0, W1, W2, out, witem, cntb, ntile_dev, nullptr, nullptr, part1, nullptr, cache_tiles, cacheA, cacheB);
    fin_kernel<<<64, 256, 0, stream>>>(part1, ntile_dev, 64, inv1);
    pass_kernel<2,1><<<NTILE_MAX, 384, 0, stream>>>(xyz, ptsT, W0, W1, W2, out, witem, cntb, ntile_dev, inv1, nullptr, part2, nullptr, cache_tiles, cacheA, cacheB);
    fin_kernel<<<64, 256, 0, stream>>>(part2, ntile_dev, 64, inv2);
    pass_kernel<3,1><<<NTILE_MAX, 384, 0, stream>>>(xyz, ptsT, W0, W1, W2, out, witem, cntb, ntile_dev, inv1, inv2, part3, out1, cache_tiles, cacheA, cacheB);
  } else {
    pass_kernel<1,0><<<NTILE_MAX, 384, 0, stream>>>(xyz, pts, W0, W1, W2, out, witem, cntb, ntile_dev, nullptr, nullptr, part1, nullptr, cache_tiles, cacheA, cacheB);
    fin_kernel<<<64, 256, 0, stream>>>(part1, ntile_dev, 64, inv1);
    pass_kernel<2,0><<<NTILE_MAX, 384, 0, stream>>>(xyz, pts, W0, W1, W2, out, witem, cntb, ntile_dev, inv1, nullptr, part2, nullptr, cache_tiles, cacheA, cacheB);
    fin_kernel<<<64, 256, 0, stream>>>(part2, ntile_dev, 64, inv2);
    pass_kernel<3,0><<<NTILE_MAX, 384, 0, stream>>>(xyz, pts, W0, W1, W2, out, witem, cntb, ntile_dev, inv1, inv2, part3, out1, cache_tiles, cacheA, cacheB);
  }
  fin3_scale<<<128, 256, 0, stream>>>(part3, ntile_dev, out);
}